// Round 13
// baseline (1244.324 us; speedup 1.0000x reference)
//
#include <hip/hip_runtime.h>

#define NN 10000      // nodes
#define NE 160000     // edges
#define NGB 100       // graphs
#define NBLK 1024     // mega-kernel grid: 4 blocks/CU x 256 CU, co-resident by construction

typedef __attribute__((ext_vector_type(8))) short s8v;     // 8 x bf16
typedef __attribute__((ext_vector_type(4))) float f4v;     // MFMA accumulator
typedef __attribute__((ext_vector_type(2))) _Float16 h2v;  // half2
typedef __attribute__((ext_vector_type(8))) _Float16 h8v;  // 8 x f16 (MFMA operand)

static __device__ __forceinline__ float lrelu(float v){ return v > 0.f ? v : 0.2f*v; }
static __device__ __forceinline__ unsigned short f2bf(float f){
  unsigned u = __float_as_uint(f);
  u += 0x7fffu + ((u >> 16) & 1u);
  return (unsigned short)(u >> 16);
}
static __device__ __forceinline__ float bf2f(unsigned short h){
  return __uint_as_float(((unsigned)h) << 16);
}
static __device__ __forceinline__ unsigned pkh(float a, float b){
  auto h = __builtin_amdgcn_cvt_pkrtz(a, b);
  return __builtin_bit_cast(unsigned, h);
}
static __device__ __forceinline__ unsigned short f2h(float f){
  _Float16 h = (_Float16)f;
  return __builtin_bit_cast(unsigned short, h);
}
static __device__ __forceinline__ float h2f(unsigned short u){
  return (float)__builtin_bit_cast(_Float16, u);
}

// ---- software grid barrier: monotonic counter; all NBLK blocks co-resident ----
static __device__ __forceinline__ void gridbar(int* bar, int target){
  __syncthreads();
  if (threadIdx.x == 0){
    __threadfence();                      // release: publish this block's writes
    atomicAdd(bar, 1);
    while (__hip_atomic_load(bar, __ATOMIC_RELAXED, __HIP_MEMORY_SCOPE_AGENT) < target)
      __builtin_amdgcn_s_sleep(2);
    __threadfence();                      // acquire: invalidate L1, see remote writes
  }
  __syncthreads();
}

// ---------------- prep: degrees + graph bounds + ALL weight packs ----------------
__global__ __launch_bounds__(256) void k_prep(const int* __restrict__ src, const int* __restrict__ dst,
    const int* __restrict__ batch,
    const float* __restrict__ We1, const float* __restrict__ be1,
    const float* __restrict__ We2, const float* __restrict__ We3,
    int* deg_src, int* deg_dst, int* starts,
    unsigned short* __restrict__ W1p, unsigned short* __restrict__ W2p,
    unsigned short* __restrict__ W3h, unsigned short* __restrict__ W3l){
  int i = blockIdx.x*256 + threadIdx.x;
  if (i < NE){ atomicAdd(&deg_src[src[i]],1); atomicAdd(&deg_dst[dst[i]],1); }
  if (i <= NN){
    int cur  = (i==NN) ? NGB : batch[i];
    int prev = (i==0)  ? -1  : batch[i-1];
    for (int b=prev+1; b<=cur; b++) if (b<=NGB) starts[b]=i;
  }
  int tid = threadIdx.x;
  if (blockIdx.x == 32){
    for (int idx=tid; idx<512; idx+=256){
      int j=idx>>6, l=idx&63, col=l&15, g=l>>4;
      int out = j*16+col;
      #pragma unroll
      for (int jj=0;jj<8;jj++){
        int k = g*8+jj;
        float v = (k<16) ? We1[k*128+out] : (k==16 ? be1[out] : 0.f);
        W1p[idx*8+jj] = f2bf(v);
      }
    }
    for (int idx=tid; idx<1024; idx+=256){
      int ft=idx>>6, l=idx&63, col=l&15, g=l>>4;
      int t=ft>>2, jo=ft&3;
      int out = jo*16+col;
      #pragma unroll
      for (int jj=0;jj<8;jj++){
        int k = t*32+g*8+jj;
        W2p[idx*8+jj] = f2bf(We2[k*64+out]);
      }
    }
  } else if (blockIdx.x < 32){
    int idx = blockIdx.x*256 + tid;   // [0, 8192)
    int jt = idx>>6, l = idx&63;
    int j = jt*16 + (l&15);
    int f0 = (l>>4)*8;
    int k = j>>5, o = j&31;
    #pragma unroll
    for (int jj=0;jj<8;jj++){
      float v = We3[(size_t)k*1024 + (size_t)(f0+jj)*32 + o];
      unsigned short h = f2bf(v);
      float r = v - bf2f(h);
      W3h[(size_t)idx*8+jj] = h;
      W3l[(size_t)idx*8+jj] = f2bf(r);
    }
  }
}

__global__ __launch_bounds__(1024) void k_scan(const int* __restrict__ deg_src, const int* __restrict__ deg_dst,
                                               int* rp_src, int* rp_dst){
  const int* deg = (blockIdx.x==0) ? deg_src : deg_dst;
  int* rp = (blockIdx.x==0) ? rp_src : rp_dst;
  __shared__ int part[1024];
  int tid = threadIdx.x;
  const int per = (NN + 1023)/1024;   // 10
  int base = tid*per;
  int s = 0;
  for (int i=0;i<per;i++){ int idx=base+i; if (idx<NN) s += deg[idx]; }
  part[tid]=s; __syncthreads();
  for (int off=1; off<1024; off<<=1){
    int v = part[tid];
    int add = (tid>=off) ? part[tid-off] : 0;
    __syncthreads();
    part[tid] = v + add;
    __syncthreads();
  }
  int run = (tid==0) ? 0 : part[tid-1];
  for (int i=0;i<per;i++){ int idx=base+i; if (idx<NN){ rp[idx]=run; run += deg[idx]; } }
  if (tid==1023) rp[NN] = part[1023];
}

__global__ __launch_bounds__(256) void k_fill(const int* __restrict__ src, const int* __restrict__ dst,
                       const int* __restrict__ rp_src, const int* __restrict__ rp_dst,
                       int* fill_src, int* fill_dst, int* pos_src, int* dstp, int* srcd){
  int i = blockIdx.x*256 + threadIdx.x;
  if (i < NE){
    int s=src[i], d=dst[i];
    int p=rp_src[s]+atomicAdd(&fill_src[s],1); pos_src[i]=p; dstp[p]=d;
    int q=rp_dst[d]+atomicAdd(&fill_dst[d],1); srcd[q]=s;
  }
}

// ---------------- fused: edge-MLP (blocks 0..624) | Y (625..937) | xb/agg (938..1001) ----------------
__global__ __launch_bounds__(256) void k_big(const float* __restrict__ ea,
    const unsigned short* __restrict__ W1p, const unsigned short* __restrict__ W2p,
    const float* __restrict__ be2, const int* __restrict__ pos_src, unsigned* __restrict__ t2b,
    const float* __restrict__ x,
    const unsigned short* __restrict__ W3h, const unsigned short* __restrict__ W3l,
    unsigned* __restrict__ Yp,
    const float* __restrict__ be3, const float* __restrict__ Wroot, const float* __restrict__ bc1,
    float* __restrict__ xb, float* __restrict__ agg){
  __shared__ unsigned short st1[4*2048];
  int bid = blockIdx.x;
  int tid=threadIdx.x, wave=tid>>6, lane=tid&63;
  const f4v fz = {0.f,0.f,0.f,0.f};
  if (bid < 625){
    int c = lane&15, g = lane>>4;
    s8v w1f[8], w2f[16];
    #pragma unroll
    for (int j=0;j<8;j++)  w1f[j] = *(const s8v*)(W1p + (size_t)(j*64+lane)*8);
    #pragma unroll
    for (int q=0;q<16;q++) w2f[q] = *(const s8v*)(W2p + (size_t)(q*64+lane)*8);
    float be2v[16];
    #pragma unroll
    for (int jo=0;jo<4;jo++)
      #pragma unroll
      for (int r=0;r<4;r++) be2v[jo*4+r] = be2[jo*16+g*4+r];
    char* myld = (char*)(st1 + wave*2048);
    for (int base = bid*64; base < NE; base += 625*64){
      int e0 = base + wave*16;
      s8v eaf = {0,0,0,0,0,0,0,0};
      if (g < 2){
        const float* p = ea + (size_t)(e0+c)*16 + g*8;
        float4 a = *(const float4*)p;
        float4 b = *(const float4*)(p+4);
        eaf[0]=(short)f2bf(a.x); eaf[1]=(short)f2bf(a.y); eaf[2]=(short)f2bf(a.z); eaf[3]=(short)f2bf(a.w);
        eaf[4]=(short)f2bf(b.x); eaf[5]=(short)f2bf(b.y); eaf[6]=(short)f2bf(b.z); eaf[7]=(short)f2bf(b.w);
      } else if (g == 2){
        eaf[0] = (short)0x3f80;
      }
      f4v acc1[8];
      #pragma unroll
      for (int j=0;j<8;j++)
        acc1[j] = __builtin_amdgcn_mfma_f32_16x16x32_bf16(w1f[j], eaf, fz, 0, 0, 0);
      #pragma unroll
      for (int j=0;j<8;j++){
        unsigned lo = (unsigned)f2bf(fmaxf(acc1[j][0],0.f)) | ((unsigned)f2bf(fmaxf(acc1[j][1],0.f))<<16);
        unsigned hi = (unsigned)f2bf(fmaxf(acc1[j][2],0.f)) | ((unsigned)f2bf(fmaxf(acc1[j][3],0.f))<<16);
        unsigned off = (unsigned)(c*256 + ((j*32 + g*8) ^ (c<<4)));
        *(uint2*)(myld + off) = make_uint2(lo, hi);
      }
      __syncthreads();
      f4v acc2[4];
      #pragma unroll
      for (int jo=0;jo<4;jo++) acc2[jo] = fz;
      #pragma unroll
      for (int t=0;t<4;t++){
        unsigned off = (unsigned)(c*256 + ((t*64 + g*16) ^ (c<<4)));
        s8v b2 = *(const s8v*)(myld + off);
        #pragma unroll
        for (int jo=0;jo<4;jo++)
          acc2[jo] = __builtin_amdgcn_mfma_f32_16x16x32_bf16(w2f[t*4+jo], b2, acc2[jo], 0, 0, 0);
      }
      int pos = pos_src[e0+c];
      unsigned* orow = t2b + (size_t)pos*32;
      #pragma unroll
      for (int jo=0;jo<4;jo++){
        float v0 = fmaxf(acc2[jo][0] + be2v[jo*4+0], 0.f);
        float v1 = fmaxf(acc2[jo][1] + be2v[jo*4+1], 0.f);
        float v2 = fmaxf(acc2[jo][2] + be2v[jo*4+2], 0.f);
        float v3 = fmaxf(acc2[jo][3] + be2v[jo*4+3], 0.f);
        *(uint2*)(orow + jo*8 + g*2) = make_uint2(pkh(v0,v1), pkh(v2,v3));
      }
      __syncthreads();
    }
  } else if (bid < 938){
    int c = lane&15, g = lane>>4;
    int tile = (bid-625)*2 + (wave>>1);
    if (tile >= 625) return;
    int jhalf = wave&1;
    int n = tile*16 + c;
    const float* xr = x + (size_t)n*32 + g*8;
    float4 xa = *(const float4*)xr;
    float4 xc = *(const float4*)(xr+4);
    float xv[8] = {xa.x,xa.y,xa.z,xa.w,xc.x,xc.y,xc.z,xc.w};
    s8v bh, bl;
    #pragma unroll
    for (int jj=0;jj<8;jj++){
      unsigned short h = f2bf(xv[jj]);
      bh[jj] = (short)h;
      bl[jj] = (short)f2bf(xv[jj] - bf2f(h));
    }
    unsigned* Yrow = Yp + (size_t)n*1024;
    for (int grp=0; grp<4; grp++){
      int jt_g0 = jhalf*64 + grp*16;
      int kpg = jhalf*4 + grp;
      uint4 Q[2][4];
      #pragma unroll
      for (int a=0; a<4; a++){
        #pragma unroll
        for (int b=0; b<2; b++){
          int jt_lo = jt_g0 + 4*a + b;
          int jt_hi = jt_lo + 2;
          s8v AhL = *(const s8v*)(W3h + (size_t)(jt_lo*64 + lane)*8);
          s8v AlL = *(const s8v*)(W3l + (size_t)(jt_lo*64 + lane)*8);
          f4v aL = __builtin_amdgcn_mfma_f32_16x16x32_bf16(AhL, bl, fz, 0, 0, 0);
          aL = __builtin_amdgcn_mfma_f32_16x16x32_bf16(AlL, bh, aL, 0, 0, 0);
          aL = __builtin_amdgcn_mfma_f32_16x16x32_bf16(AhL, bh, aL, 0, 0, 0);
          s8v AhH = *(const s8v*)(W3h + (size_t)(jt_hi*64 + lane)*8);
          s8v AlH = *(const s8v*)(W3l + (size_t)(jt_hi*64 + lane)*8);
          f4v aH = __builtin_amdgcn_mfma_f32_16x16x32_bf16(AhH, bl, fz, 0, 0, 0);
          aH = __builtin_amdgcn_mfma_f32_16x16x32_bf16(AlH, bh, aH, 0, 0, 0);
          aH = __builtin_amdgcn_mfma_f32_16x16x32_bf16(AhH, bh, aH, 0, 0, 0);
          #pragma unroll
          for (int r=0;r<4;r++){
            unsigned pv = pkh(aL[r], aH[r]);
            if (a==0) Q[b][r].x = pv;
            else if (a==1) Q[b][r].y = pv;
            else if (a==2) Q[b][r].z = pv;
            else Q[b][r].w = pv;
          }
        }
      }
      #pragma unroll
      for (int b=0;b<2;b++)
        #pragma unroll
        for (int r=0;r<4;r++){
          int o = b*16 + g*4 + r;
          *(uint4*)(Yrow + kpg*128 + o*4) = Q[b][r];
        }
    }
  } else {
    __shared__ __align__(16) float sx[8][32];
    int b2 = bid - 938;
    int oo = tid & 31, nn = tid >> 5;
    float wb[32], wr[32];
    #pragma unroll
    for (int f=0;f<32;f++){ wb[f]=be3[f*32+oo]; wr[f]=Wroot[f*32+oo]; }
    float bcv = bc1[oo];
    int per = (1250 + 63)/64;
    int g0 = b2*per, g1 = min(g0+per, 1250);
    for (int gi=g0; gi<g1; gi++){
      int nb = gi*8;
      __syncthreads();
      sx[tid>>5][tid&31] = x[(size_t)nb*32 + tid];
      __syncthreads();
      float a1=0.f, a2=0.f;
      #pragma unroll
      for (int f4=0;f4<8;f4++){
        float4 xvv = *(const float4*)(&sx[nn][f4*4]);
        a1 += xvv.x*wb[f4*4+0]+xvv.y*wb[f4*4+1]+xvv.z*wb[f4*4+2]+xvv.w*wb[f4*4+3];
        a2 += xvv.x*wr[f4*4+0]+xvv.y*wr[f4*4+1]+xvv.z*wr[f4*4+2]+xvv.w*wr[f4*4+3];
      }
      xb[(size_t)(nb+nn)*32+oo] = a1;
      agg[(size_t)(nb+nn)*32+oo] = a2 + bcv;
    }
  }
}

// =============== mega-kernel phases ===============

static __device__ void msg_phase(const unsigned* __restrict__ Yp,
    const float* __restrict__ xb, const unsigned* __restrict__ t2b,
    const int* __restrict__ rp_src, const int* __restrict__ dstp,
    float* __restrict__ agg){
  int tid=threadIdx.x, w=tid>>6, lane=tid&63;
  int c = lane&15, g = lane>>4;
  int gw = blockIdx.x*4 + w;
  const f4v fz = {0.f,0.f,0.f,0.f};
  for (int n=gw; n<NN; n+=NBLK*4){
    int beg=rp_src[n], end=rp_src[n+1];
    if (beg==end) continue;
    const unsigned* Yr = Yp + (size_t)n*1024;
    h8v B[2][2];
    #pragma unroll
    for (int kt=0;kt<2;kt++)
      #pragma unroll
      for (int jn=0;jn<2;jn++)
        B[kt][jn] = __builtin_bit_cast(h8v, *(const uint4*)(Yr + (kt*4+g)*128 + (jn*16+c)*4));
    float xq0 = xb[(size_t)n*32 + c];
    float xq1 = xb[(size_t)n*32 + c + 16];
    for (int eb=beg; eb<end; eb+=16){
      const unsigned* tr = t2b + (size_t)(eb + c)*32;
      h8v A0 = __builtin_bit_cast(h8v, *(const uint4*)(tr + g*4));
      h8v A1 = __builtin_bit_cast(h8v, *(const uint4*)(tr + 16 + g*4));
      f4v acc0 = __builtin_amdgcn_mfma_f32_16x16x32_f16(A0, B[0][0], fz, 0, 0, 0);
      acc0 = __builtin_amdgcn_mfma_f32_16x16x32_f16(A1, B[1][0], acc0, 0, 0, 0);
      f4v acc1 = __builtin_amdgcn_mfma_f32_16x16x32_f16(A0, B[0][1], fz, 0, 0, 0);
      acc1 = __builtin_amdgcn_mfma_f32_16x16x32_f16(A1, B[1][1], acc1, 0, 0, 0);
      #pragma unroll
      for (int r=0;r<4;r++){
        int p = eb + g*4 + r;
        if (p < end){
          int d = dstp[p];
          float* ap = agg + (size_t)d*32;
          unsafeAtomicAdd(ap + c,      acc0[r] + xq0);
          unsafeAtomicAdd(ap + c + 16, acc1[r] + xq1);
        }
      }
    }
  }
}

static __device__ void stats_phase(const float* __restrict__ buf, int nrows, int ncols,
                                   float* __restrict__ stats, char* smem){
  if (blockIdx.x >= 64) return;
  int tid = threadIdx.x;
  int c  = tid % ncols;
  int r0 = tid / ncols;
  int rp = 256 / ncols;
  float s1=0.f, s2=0.f;
  for (int base=blockIdx.x*rp; base<nrows; base+=64*rp){
    int r = base + r0;
    if (r < nrows){
      float v = buf[(size_t)r*ncols + c];
      s1 += v; s2 += v*v;
    }
  }
  float* A = (float*)smem;
  float* B = A + 256;
  A[tid]=s1; B[tid]=s2; __syncthreads();
  if (tid < ncols){
    float t1=0.f, t2=0.f;
    for (int gg=0; gg<256/ncols; gg++){ t1 += A[gg*ncols+tid]; t2 += B[gg*ncols+tid]; }
    atomicAdd(&stats[tid], t1);
    atomicAdd(&stats[ncols+tid], t2);
  }
}

template<int FIN, int FOUT>
static __device__ void linear_phase(const float* __restrict__ raw,
    const float* __restrict__ stats, const float* __restrict__ W,
    const float* __restrict__ avs, const float* __restrict__ avd,
    unsigned short* __restrict__ hWh, float* __restrict__ sc_s, float* __restrict__ sc_d,
    char* smem){
  float* sW = (float*)smem;
  float* sA = sW + FIN*FOUT;
  float* sD = sA + FOUT;
  float* sScale = sD + FOUT;
  float* sShift = sScale + FIN;
  float* sIn = sShift + FIN;   // [4][FIN]
  int tid = threadIdx.x;
  for (int i=tid;i<FIN*FOUT;i+=256) sW[i]=W[i];
  if (tid<FOUT){ sA[tid]=avs[tid]; sD[tid]=avd[tid]; }
  if (tid<FIN){
    float m = stats[tid]*(1.f/NN);
    float v = stats[FIN+tid]*(1.f/NN) - m*m;
    float s = rsqrtf(v + 1e-5f);
    sScale[tid]=s; sShift[tid]=-m*s;
  }
  __syncthreads();
  int wave=tid>>6, lane=tid&63;
  for (int nb = blockIdx.x*4; nb < NN; nb += NBLK*4){
    int n = nb + wave;
    bool act = n < NN;
    if (act){
      for (int ff=lane; ff<FIN; ff+=64){
        float vv = raw[(size_t)n*FIN+ff]*sScale[ff]+sShift[ff];
        sIn[wave*FIN+ff] = fmaxf(vv, 0.f);
      }
    }
    __syncthreads();
    if (act){
      float out0=0.f, out1=0.f;
      #pragma unroll
      for (int ff=0; ff<FIN; ff++){
        float xv = sIn[wave*FIN+ff];
        out0 += xv*sW[ff*FOUT+lane];
        if constexpr (FOUT > 64) out1 += xv*sW[ff*FOUT+lane+64];
      }
      hWh[(size_t)n*FOUT + lane] = f2h(out0);
      float ps = out0*sA[lane], pd = out0*sD[lane];
      if constexpr (FOUT > 64){
        hWh[(size_t)n*FOUT + lane + 64] = f2h(out1);
        ps += out1*sA[lane+64]; pd += out1*sD[lane+64];
      }
      #pragma unroll
      for (int off=32;off>0;off>>=1){ ps += __shfl_down(ps,off); pd += __shfl_down(pd,off); }
      if (lane==0){ sc_s[n]=ps; sc_d[n]=pd; }
    }
    __syncthreads();
  }
}

template<int F>
static __device__ void attn_phase(const unsigned short* __restrict__ hWh,
    const float* __restrict__ sc_s, const float* __restrict__ sc_d,
    const int* __restrict__ rp_dst, const int* __restrict__ srcd,
    const float* __restrict__ bias, float* __restrict__ outraw){
  int tid=threadIdx.x, w=tid>>6, lane=tid&63;
  int gw = blockIdx.x*4 + w;
  for (int n=gw; n<NN; n+=NBLK*4){
    int beg=rp_dst[n], end=rp_dst[n+1];
    float scd = sc_d[n];
    float M=-3e38f, S=0.f, acc0=0.f, acc1=0.f;
    for (int base=beg; base<end; base+=64){
      int nb = min(64, end-base);
      float sc=-3e38f; int si=0;
      if (lane<nb){ si = srcd[base+lane]; sc = lrelu(sc_s[si]+scd); }
      float cm=sc;
      #pragma unroll
      for (int off=32;off>0;off>>=1) cm = fmaxf(cm, __shfl_xor(cm,off));
      float Mn = fmaxf(M, cm);
      float p = (lane<nb) ? __expf(sc-Mn) : 0.f;
      float ps=p;
      #pragma unroll
      for (int off=32;off>0;off>>=1) ps += __shfl_xor(ps,off);
      float scale = __expf(M-Mn);
      S = S*scale + ps;
      acc0*=scale; acc1*=scale;
      int jj=0;
      for (; jj+4<=nb; jj+=4){
        float p0=__shfl(p,jj), p1=__shfl(p,jj+1), p2=__shfl(p,jj+2), p3=__shfl(p,jj+3);
        int   q0=__shfl(si,jj), q1=__shfl(si,jj+1), q2=__shfl(si,jj+2), q3=__shfl(si,jj+3);
        if constexpr (F==128){
          unsigned u0 = *(const unsigned*)(hWh + (size_t)q0*128 + 2*lane);
          unsigned u1 = *(const unsigned*)(hWh + (size_t)q1*128 + 2*lane);
          unsigned u2 = *(const unsigned*)(hWh + (size_t)q2*128 + 2*lane);
          unsigned u3 = *(const unsigned*)(hWh + (size_t)q3*128 + 2*lane);
          acc0 += p0*h2f((unsigned short)(u0&0xffffu)); acc1 += p0*h2f((unsigned short)(u0>>16));
          acc0 += p1*h2f((unsigned short)(u1&0xffffu)); acc1 += p1*h2f((unsigned short)(u1>>16));
          acc0 += p2*h2f((unsigned short)(u2&0xffffu)); acc1 += p2*h2f((unsigned short)(u2>>16));
          acc0 += p3*h2f((unsigned short)(u3&0xffffu)); acc1 += p3*h2f((unsigned short)(u3>>16));
        } else {
          float v0 = h2f(hWh[(size_t)q0*64+lane]);
          float v1 = h2f(hWh[(size_t)q1*64+lane]);
          float v2 = h2f(hWh[(size_t)q2*64+lane]);
          float v3 = h2f(hWh[(size_t)q3*64+lane]);
          acc0 += p0*v0 + p1*v1 + p2*v2 + p3*v3;
        }
      }
      for (; jj<nb; jj++){
        float pj=__shfl(p,jj); int qj=__shfl(si,jj);
        if constexpr (F==128){
          unsigned u = *(const unsigned*)(hWh + (size_t)qj*128 + 2*lane);
          acc0 += pj*h2f((unsigned short)(u&0xffffu));
          acc1 += pj*h2f((unsigned short)(u>>16));
        } else {
          acc0 += pj*h2f(hWh[(size_t)qj*64+lane]);
        }
      }
      M = Mn;
    }
    float sself = lrelu(sc_s[n]+scd);
    float Mn = fmaxf(M, sself);
    float scale = __expf(M-Mn);
    float pself = __expf(sself-Mn);
    S = S*scale + pself;
    acc0*=scale; acc1*=scale;
    float inv = 1.f/(S+1e-16f);
    if constexpr (F==128){
      unsigned u = *(const unsigned*)(hWh + (size_t)n*128 + 2*lane);
      acc0 += pself*h2f((unsigned short)(u&0xffffu));
      acc1 += pself*h2f((unsigned short)(u>>16));
      float ox = acc0*inv + bias[2*lane];
      float oy = acc1*inv + bias[2*lane+1];
      *(float2*)(outraw + (size_t)n*128 + 2*lane) = make_float2(ox, oy);
    } else {
      acc0 += pself*h2f(hWh[(size_t)n*64+lane]);
      outraw[(size_t)n*64+lane] = acc0*inv + bias[lane];
    }
  }
}

static __device__ void poolhead1_phase(const float* __restrict__ h2raw,
    const float* __restrict__ stats, const int* __restrict__ starts,
    const float* __restrict__ Wf1, const float* __restrict__ bf1,
    float* __restrict__ g1, float* __restrict__ statsH1, char* smem){
  if (blockIdx.x >= NGB) return;
  float* sc = (float*)smem;          // 128
  float* sh = sc + 128;              // 128
  float* red = sh + 128;             // 256
  float* sg = red + 256;             // 128
  int b=blockIdx.x, t=threadIdx.x;
  if (t<128){
    float m = stats[t]*(1.f/NN);
    float v = stats[128+t]*(1.f/NN) - m*m;
    float s = rsqrtf(v+1e-5f);
    sc[t]=s; sh[t]=-m*s;
  }
  __syncthreads();
  int s0=starts[b], s1=starts[b+1];
  int f=t&127, half=t>>7;
  float acc=0.f;
  for (int n=s0+half;n<s1;n+=2){
    float v = h2raw[(size_t)n*128+f]*sc[f]+sh[f];
    acc += fmaxf(v,0.f);
  }
  red[t]=acc; __syncthreads();
  if (half==0){
    int cnt = s1-s0;
    sg[f] = (red[f]+red[128+f]) / fmaxf((float)cnt, 1.f);
  }
  __syncthreads();
  float a = bf1[t];
  #pragma unroll 4
  for (int k=0;k<128;k++) a += sg[k]*Wf1[k*256+t];
  g1[b*256+t]=a;
  atomicAdd(&statsH1[t], a);
  atomicAdd(&statsH1[256+t], a*a);
}

static __device__ void head2_phase(const float* __restrict__ g1,
    const float* __restrict__ stats, const float* __restrict__ Wf2,
    const float* __restrict__ bf2, float* __restrict__ g2, float* __restrict__ statsH2,
    char* smem){
  if (blockIdx.x >= NGB) return;
  float* sin_ = (float*)smem;        // 256
  int r=blockIdx.x, t=threadIdx.x;
  float m = stats[t]*(1.f/NGB);
  float v = stats[256+t]*(1.f/NGB) - m*m;
  float val = (g1[r*256+t]-m)*rsqrtf(v+1e-5f);
  sin_[t]=fmaxf(val,0.f);
  __syncthreads();
  if (t<128){
    float acc=bf2[t];
    #pragma unroll 4
    for (int k=0;k<256;k++) acc += sin_[k]*Wf2[k*128+t];
    g2[r*128+t]=acc;
    atomicAdd(&statsH2[t], acc);
    atomicAdd(&statsH2[128+t], acc*acc);
  }
}

static __device__ void head3_phase(const float* __restrict__ g2,
    const float* __restrict__ stats, const float* __restrict__ Wf3,
    const float* __restrict__ bf3, float* __restrict__ out, char* smem){
  if (blockIdx.x >= NGB) return;
  float* sin_ = (float*)smem;        // 128
  int r=blockIdx.x, t=threadIdx.x;
  if (t<128){
    float m = stats[t]*(1.f/NGB);
    float v = stats[128+t]*(1.f/NGB) - m*m;
    float val = (g2[r*128+t]-m)*rsqrtf(v+1e-5f);
    sin_[t]=fmaxf(val,0.f);
  }
  __syncthreads();
  if (t<64){
    float acc=bf3[t];
    #pragma unroll 4
    for (int k=0;k<128;k++) acc += sin_[k]*Wf3[k*64+t];
    out[r*64+t]=acc;
  }
}

// =============== the mega-kernel: msg -> GAT x2 -> pool -> head, software grid barriers ===============
__global__ __launch_bounds__(256, 4) void k_mega(
    const unsigned* __restrict__ Yp, const float* __restrict__ xb, const unsigned* __restrict__ t2b,
    const int* __restrict__ rp_src, const int* __restrict__ dstp, float* __restrict__ agg,
    const int* __restrict__ rp_dst, const int* __restrict__ srcd,
    float* __restrict__ stats0, float* __restrict__ stats1, float* __restrict__ stats2,
    const float* __restrict__ Wg1, const float* __restrict__ as1, const float* __restrict__ ad1, const float* __restrict__ bg1,
    const float* __restrict__ Wg2, const float* __restrict__ as2, const float* __restrict__ ad2, const float* __restrict__ bg2,
    unsigned short* __restrict__ hW1, float* __restrict__ scs1, float* __restrict__ scd1, float* __restrict__ h1,
    unsigned short* __restrict__ hW2, float* __restrict__ scs2, float* __restrict__ scd2, float* __restrict__ h2,
    const int* __restrict__ starts, const float* __restrict__ Wf1, const float* __restrict__ bf1,
    float* __restrict__ g1, float* __restrict__ statsH1,
    const float* __restrict__ Wf2, const float* __restrict__ bf2, float* __restrict__ g2, float* __restrict__ statsH2,
    const float* __restrict__ Wf3, const float* __restrict__ bf3, float* __restrict__ out,
    int* __restrict__ bar){
  __shared__ __align__(16) char smem[35840];   // max phase need: linear<64,128> = 35328 B
  int tgt = NBLK;
  msg_phase(Yp, xb, t2b, rp_src, dstp, agg);
  gridbar(bar, tgt); tgt += NBLK;
  stats_phase(agg, NN, 32, stats0, smem);
  gridbar(bar, tgt); tgt += NBLK;
  linear_phase<32,64>(agg, stats0, Wg1, as1, ad1, hW1, scs1, scd1, smem);
  gridbar(bar, tgt); tgt += NBLK;
  attn_phase<64>(hW1, scs1, scd1, rp_dst, srcd, bg1, h1);
  gridbar(bar, tgt); tgt += NBLK;
  stats_phase(h1, NN, 64, stats1, smem);
  gridbar(bar, tgt); tgt += NBLK;
  linear_phase<64,128>(h1, stats1, Wg2, as2, ad2, hW2, scs2, scd2, smem);
  gridbar(bar, tgt); tgt += NBLK;
  attn_phase<128>(hW2, scs2, scd2, rp_dst, srcd, bg2, h2);
  gridbar(bar, tgt); tgt += NBLK;
  stats_phase(h2, NN, 128, stats2, smem);
  gridbar(bar, tgt); tgt += NBLK;
  poolhead1_phase(h2, stats2, starts, Wf1, bf1, g1, statsH1, smem);
  gridbar(bar, tgt); tgt += NBLK;
  head2_phase(g1, statsH1, Wf2, bf2, g2, statsH2, smem);
  gridbar(bar, tgt); tgt += NBLK;
  head3_phase(g2, statsH2, Wf3, bf3, out, smem);
}

extern "C" void kernel_launch(void* const* d_in, const int* in_sizes, int n_in,
                              void* d_out, int out_size, void* d_ws, size_t ws_size,
                              hipStream_t stream){
  const float* x    = (const float*)d_in[0];
  const int*   ei   = (const int*)d_in[1];
  const float* ea   = (const float*)d_in[2];
  const int*   batch= (const int*)d_in[3];
  const float* We1=(const float*)d_in[4];  const float* be1=(const float*)d_in[5];
  const float* We2=(const float*)d_in[6];  const float* be2=(const float*)d_in[7];
  const float* We3=(const float*)d_in[8];  const float* be3=(const float*)d_in[9];
  const float* Wroot=(const float*)d_in[10]; const float* bc1=(const float*)d_in[11];
  const float* Wg1=(const float*)d_in[12]; const float* as1=(const float*)d_in[13];
  const float* ad1=(const float*)d_in[14]; const float* bg1=(const float*)d_in[15];
  const float* Wg2=(const float*)d_in[16]; const float* as2=(const float*)d_in[17];
  const float* ad2=(const float*)d_in[18]; const float* bg2=(const float*)d_in[19];
  const float* Wf1=(const float*)d_in[20]; const float* bf1=(const float*)d_in[21];
  const float* Wf2=(const float*)d_in[22]; const float* bf2=(const float*)d_in[23];
  const float* Wf3=(const float*)d_in[24]; const float* bf3=(const float*)d_in[25];
  (void)in_sizes; (void)n_in; (void)out_size; (void)ws_size;
  float* out = (float*)d_out;
  char* ws = (char*)d_ws;
  const int* srcA = ei;
  const int* dstA = ei + NE;

  size_t off = 0;
  auto take = [&](size_t bytes)->size_t{ size_t r = off; off += (bytes + 255) & ~(size_t)255; return r; };
  // zero region (memset runs inside the graph -> re-zeroed every replay, incl. barrier counter)
  size_t o_deg_src = take(NN*4), o_deg_dst = take(NN*4);
  size_t o_fill_src = take(NN*4), o_fill_dst = take(NN*4);
  size_t o_stats0 = take(2*32*4), o_stats1 = take(2*64*4), o_stats2 = take(2*128*4);
  size_t o_statsH1 = take(2*256*4), o_statsH2 = take(2*128*4);
  size_t o_bar = take(256);
  size_t zero_bytes = off;
  // rest
  size_t o_rp_src = take((NN+1)*4), o_rp_dst = take((NN+1)*4);
  size_t o_pos_src = take((size_t)NE*4);
  size_t o_dstp = take((size_t)NE*4);
  size_t o_srcd = take((size_t)NE*4);
  size_t o_starts = take((NGB+1)*4);
  size_t o_W1p = take(4096*2);
  size_t o_W2p = take(8192*2);
  size_t o_W3h = take((size_t)128*64*8*2);
  size_t o_W3l = take((size_t)128*64*8*2);
  size_t o_t2b = take((size_t)(NE+16)*32*4);       // f16 k-pairs, pad for MFMA tail
  size_t o_Yp  = take((size_t)NN*1024*4);          // f16 k-pairs, kpg-major
  size_t o_xb  = take((size_t)NN*32*4);
  size_t o_agg = take((size_t)NN*32*4);
  size_t o_hW1 = take((size_t)NN*64*2);
  size_t o_scs1 = take(NN*4), o_scd1 = take(NN*4);
  size_t o_h1  = take((size_t)NN*64*4);
  size_t o_hW2 = take((size_t)NN*128*2);
  size_t o_scs2 = take(NN*4), o_scd2 = take(NN*4);
  size_t o_h2  = take((size_t)NN*128*4);
  size_t o_g1  = take(NGB*256*4);
  size_t o_g2  = take(NGB*128*4);

  #define WF(o) ((float*)(ws + (o)))
  #define WI(o) ((int*)(ws + (o)))
  #define WU(o) ((unsigned short*)(ws + (o)))
  #define WW(o) ((unsigned*)(ws + (o)))

  (void)hipMemsetAsync(ws, 0, zero_bytes, stream);
  k_prep<<<625,256,0,stream>>>(srcA,dstA,batch,We1,be1,We2,We3,
                               WI(o_deg_src),WI(o_deg_dst),WI(o_starts),
                               WU(o_W1p),WU(o_W2p),WU(o_W3h),WU(o_W3l));
  k_scan<<<2,1024,0,stream>>>(WI(o_deg_src),WI(o_deg_dst),WI(o_rp_src),WI(o_rp_dst));
  k_fill<<<625,256,0,stream>>>(srcA,dstA,WI(o_rp_src),WI(o_rp_dst),
                               WI(o_fill_src),WI(o_fill_dst),
                               WI(o_pos_src),WI(o_dstp),WI(o_srcd));
  k_big<<<1002,256,0,stream>>>(ea,WU(o_W1p),WU(o_W2p),be2,WI(o_pos_src),WW(o_t2b),
                               x,WU(o_W3h),WU(o_W3l),WW(o_Yp),
                               be3,Wroot,bc1,WF(o_xb),WF(o_agg));
  k_mega<<<NBLK,256,0,stream>>>(WW(o_Yp),WF(o_xb),WW(o_t2b),
                                WI(o_rp_src),WI(o_dstp),WF(o_agg),
                                WI(o_rp_dst),WI(o_srcd),
                                WF(o_stats0),WF(o_stats1),WF(o_stats2),
                                Wg1,as1,ad1,bg1, Wg2,as2,ad2,bg2,
                                WU(o_hW1),WF(o_scs1),WF(o_scd1),WF(o_h1),
                                WU(o_hW2),WF(o_scs2),WF(o_scd2),WF(o_h2),
                                WI(o_starts),Wf1,bf1,WF(o_g1),WF(o_statsH1),
                                Wf2,bf2,WF(o_g2),WF(o_statsH2),
                                Wf3,bf3,out,
                                WI(o_bar));
}

// Round 14
// 663.392 us; speedup vs baseline: 1.8757x; 1.8757x over previous
//
#include <hip/hip_runtime.h>

#define NN 10000      // nodes
#define NE 160000     // edges
#define NGB 100       // graphs
#define NBLK 1024     // mega-kernel grid: 4 blocks/CU x 256 CU, co-resident by construction

typedef __attribute__((ext_vector_type(8))) short s8v;     // 8 x bf16
typedef __attribute__((ext_vector_type(4))) float f4v;     // MFMA accumulator
typedef __attribute__((ext_vector_type(2))) _Float16 h2v;  // half2
typedef __attribute__((ext_vector_type(8))) _Float16 h8v;  // 8 x f16 (MFMA operand)

static __device__ __forceinline__ float lrelu(float v){ return v > 0.f ? v : 0.2f*v; }
static __device__ __forceinline__ unsigned short f2bf(float f){
  unsigned u = __float_as_uint(f);
  u += 0x7fffu + ((u >> 16) & 1u);
  return (unsigned short)(u >> 16);
}
static __device__ __forceinline__ float bf2f(unsigned short h){
  return __uint_as_float(((unsigned)h) << 16);
}
static __device__ __forceinline__ unsigned pkh(float a, float b){
  auto h = __builtin_amdgcn_cvt_pkrtz(a, b);
  return __builtin_bit_cast(unsigned, h);
}
static __device__ __forceinline__ unsigned short f2h(float f){
  _Float16 h = (_Float16)f;
  return __builtin_bit_cast(unsigned short, h);
}
static __device__ __forceinline__ float h2f(unsigned short u){
  return (float)__builtin_bit_cast(_Float16, u);
}

// ---- system-scope (L1+L2-bypassing) stores: land at coherent L3, no fence needed ----
static __device__ __forceinline__ void stf(float* p, float v){
  __hip_atomic_store(p, v, __ATOMIC_RELAXED, __HIP_MEMORY_SCOPE_SYSTEM);
}
static __device__ __forceinline__ void stu(unsigned* p, unsigned v){
  __hip_atomic_store(p, v, __ATOMIC_RELAXED, __HIP_MEMORY_SCOPE_SYSTEM);
}
static __device__ __forceinline__ void stf2(float* p, float a, float b){
  float2 v = make_float2(a, b);
  __hip_atomic_store((unsigned long long*)p,
                     __builtin_bit_cast(unsigned long long, v),
                     __ATOMIC_RELAXED, __HIP_MEMORY_SCOPE_SYSTEM);
}

// ---- fence-free grid barrier: all data already at L3 via system stores/far atomics ----
static __device__ __forceinline__ void gridbar(int* bar, int target){
  __syncthreads();
  if (threadIdx.x == 0){
    asm volatile("s_waitcnt vmcnt(0)" ::: "memory");   // release: system stores acked
    __hip_atomic_fetch_add(bar, 1, __ATOMIC_RELAXED, __HIP_MEMORY_SCOPE_SYSTEM);
    while (__hip_atomic_load(bar, __ATOMIC_RELAXED, __HIP_MEMORY_SCOPE_SYSTEM) < target)
      __builtin_amdgcn_s_sleep(16);
    asm volatile("" ::: "memory");
  }
  __syncthreads();
}

// ---------------- prep: degrees + graph bounds + ALL weight packs ----------------
__global__ __launch_bounds__(256) void k_prep(const int* __restrict__ src, const int* __restrict__ dst,
    const int* __restrict__ batch,
    const float* __restrict__ We1, const float* __restrict__ be1,
    const float* __restrict__ We2, const float* __restrict__ We3,
    int* deg_src, int* deg_dst, int* starts,
    unsigned short* __restrict__ W1p, unsigned short* __restrict__ W2p,
    unsigned short* __restrict__ W3h, unsigned short* __restrict__ W3l){
  int i = blockIdx.x*256 + threadIdx.x;
  if (i < NE){ atomicAdd(&deg_src[src[i]],1); atomicAdd(&deg_dst[dst[i]],1); }
  if (i <= NN){
    int cur  = (i==NN) ? NGB : batch[i];
    int prev = (i==0)  ? -1  : batch[i-1];
    for (int b=prev+1; b<=cur; b++) if (b<=NGB) starts[b]=i;
  }
  int tid = threadIdx.x;
  if (blockIdx.x == 32){
    for (int idx=tid; idx<512; idx+=256){
      int j=idx>>6, l=idx&63, col=l&15, g=l>>4;
      int out = j*16+col;
      #pragma unroll
      for (int jj=0;jj<8;jj++){
        int k = g*8+jj;
        float v = (k<16) ? We1[k*128+out] : (k==16 ? be1[out] : 0.f);
        W1p[idx*8+jj] = f2bf(v);
      }
    }
    for (int idx=tid; idx<1024; idx+=256){
      int ft=idx>>6, l=idx&63, col=l&15, g=l>>4;
      int t=ft>>2, jo=ft&3;
      int out = jo*16+col;
      #pragma unroll
      for (int jj=0;jj<8;jj++){
        int k = t*32+g*8+jj;
        W2p[idx*8+jj] = f2bf(We2[k*64+out]);
      }
    }
  } else if (blockIdx.x < 32){
    int idx = blockIdx.x*256 + tid;   // [0, 8192)
    int jt = idx>>6, l = idx&63;
    int j = jt*16 + (l&15);
    int f0 = (l>>4)*8;
    int k = j>>5, o = j&31;
    #pragma unroll
    for (int jj=0;jj<8;jj++){
      float v = We3[(size_t)k*1024 + (size_t)(f0+jj)*32 + o];
      unsigned short h = f2bf(v);
      float r = v - bf2f(h);
      W3h[(size_t)idx*8+jj] = h;
      W3l[(size_t)idx*8+jj] = f2bf(r);
    }
  }
}

__global__ __launch_bounds__(1024) void k_scan(const int* __restrict__ deg_src, const int* __restrict__ deg_dst,
                                               int* rp_src, int* rp_dst){
  const int* deg = (blockIdx.x==0) ? deg_src : deg_dst;
  int* rp = (blockIdx.x==0) ? rp_src : rp_dst;
  __shared__ int part[1024];
  int tid = threadIdx.x;
  const int per = (NN + 1023)/1024;   // 10
  int base = tid*per;
  int s = 0;
  for (int i=0;i<per;i++){ int idx=base+i; if (idx<NN) s += deg[idx]; }
  part[tid]=s; __syncthreads();
  for (int off=1; off<1024; off<<=1){
    int v = part[tid];
    int add = (tid>=off) ? part[tid-off] : 0;
    __syncthreads();
    part[tid] = v + add;
    __syncthreads();
  }
  int run = (tid==0) ? 0 : part[tid-1];
  for (int i=0;i<per;i++){ int idx=base+i; if (idx<NN){ rp[idx]=run; run += deg[idx]; } }
  if (tid==1023) rp[NN] = part[1023];
}

__global__ __launch_bounds__(256) void k_fill(const int* __restrict__ src, const int* __restrict__ dst,
                       const int* __restrict__ rp_src, const int* __restrict__ rp_dst,
                       int* fill_src, int* fill_dst, int* pos_src, int* dstp, int* srcd){
  int i = blockIdx.x*256 + threadIdx.x;
  if (i < NE){
    int s=src[i], d=dst[i];
    int p=rp_src[s]+atomicAdd(&fill_src[s],1); pos_src[i]=p; dstp[p]=d;
    int q=rp_dst[d]+atomicAdd(&fill_dst[d],1); srcd[q]=s;
  }
}

// ---------------- fused: edge-MLP (blocks 0..624) | Y (625..937) | xb/agg (938..1001) ----------------
__global__ __launch_bounds__(256) void k_big(const float* __restrict__ ea,
    const unsigned short* __restrict__ W1p, const unsigned short* __restrict__ W2p,
    const float* __restrict__ be2, const int* __restrict__ pos_src, unsigned* __restrict__ t2b,
    const float* __restrict__ x,
    const unsigned short* __restrict__ W3h, const unsigned short* __restrict__ W3l,
    unsigned* __restrict__ Yp,
    const float* __restrict__ be3, const float* __restrict__ Wroot, const float* __restrict__ bc1,
    float* __restrict__ xb, float* __restrict__ agg){
  __shared__ unsigned short st1[4*2048];
  int bid = blockIdx.x;
  int tid=threadIdx.x, wave=tid>>6, lane=tid&63;
  const f4v fz = {0.f,0.f,0.f,0.f};
  if (bid < 625){
    int c = lane&15, g = lane>>4;
    s8v w1f[8], w2f[16];
    #pragma unroll
    for (int j=0;j<8;j++)  w1f[j] = *(const s8v*)(W1p + (size_t)(j*64+lane)*8);
    #pragma unroll
    for (int q=0;q<16;q++) w2f[q] = *(const s8v*)(W2p + (size_t)(q*64+lane)*8);
    float be2v[16];
    #pragma unroll
    for (int jo=0;jo<4;jo++)
      #pragma unroll
      for (int r=0;r<4;r++) be2v[jo*4+r] = be2[jo*16+g*4+r];
    char* myld = (char*)(st1 + wave*2048);
    for (int base = bid*64; base < NE; base += 625*64){
      int e0 = base + wave*16;
      s8v eaf = {0,0,0,0,0,0,0,0};
      if (g < 2){
        const float* p = ea + (size_t)(e0+c)*16 + g*8;
        float4 a = *(const float4*)p;
        float4 b = *(const float4*)(p+4);
        eaf[0]=(short)f2bf(a.x); eaf[1]=(short)f2bf(a.y); eaf[2]=(short)f2bf(a.z); eaf[3]=(short)f2bf(a.w);
        eaf[4]=(short)f2bf(b.x); eaf[5]=(short)f2bf(b.y); eaf[6]=(short)f2bf(b.z); eaf[7]=(short)f2bf(b.w);
      } else if (g == 2){
        eaf[0] = (short)0x3f80;
      }
      f4v acc1[8];
      #pragma unroll
      for (int j=0;j<8;j++)
        acc1[j] = __builtin_amdgcn_mfma_f32_16x16x32_bf16(w1f[j], eaf, fz, 0, 0, 0);
      #pragma unroll
      for (int j=0;j<8;j++){
        unsigned lo = (unsigned)f2bf(fmaxf(acc1[j][0],0.f)) | ((unsigned)f2bf(fmaxf(acc1[j][1],0.f))<<16);
        unsigned hi = (unsigned)f2bf(fmaxf(acc1[j][2],0.f)) | ((unsigned)f2bf(fmaxf(acc1[j][3],0.f))<<16);
        unsigned off = (unsigned)(c*256 + ((j*32 + g*8) ^ (c<<4)));
        *(uint2*)(myld + off) = make_uint2(lo, hi);
      }
      __syncthreads();
      f4v acc2[4];
      #pragma unroll
      for (int jo=0;jo<4;jo++) acc2[jo] = fz;
      #pragma unroll
      for (int t=0;t<4;t++){
        unsigned off = (unsigned)(c*256 + ((t*64 + g*16) ^ (c<<4)));
        s8v b2 = *(const s8v*)(myld + off);
        #pragma unroll
        for (int jo=0;jo<4;jo++)
          acc2[jo] = __builtin_amdgcn_mfma_f32_16x16x32_bf16(w2f[t*4+jo], b2, acc2[jo], 0, 0, 0);
      }
      int pos = pos_src[e0+c];
      unsigned* orow = t2b + (size_t)pos*32;
      #pragma unroll
      for (int jo=0;jo<4;jo++){
        float v0 = fmaxf(acc2[jo][0] + be2v[jo*4+0], 0.f);
        float v1 = fmaxf(acc2[jo][1] + be2v[jo*4+1], 0.f);
        float v2 = fmaxf(acc2[jo][2] + be2v[jo*4+2], 0.f);
        float v3 = fmaxf(acc2[jo][3] + be2v[jo*4+3], 0.f);
        *(uint2*)(orow + jo*8 + g*2) = make_uint2(pkh(v0,v1), pkh(v2,v3));
      }
      __syncthreads();
    }
  } else if (bid < 938){
    int c = lane&15, g = lane>>4;
    int tile = (bid-625)*2 + (wave>>1);
    if (tile >= 625) return;
    int jhalf = wave&1;
    int n = tile*16 + c;
    const float* xr = x + (size_t)n*32 + g*8;
    float4 xa = *(const float4*)xr;
    float4 xc = *(const float4*)(xr+4);
    float xv[8] = {xa.x,xa.y,xa.z,xa.w,xc.x,xc.y,xc.z,xc.w};
    s8v bh, bl;
    #pragma unroll
    for (int jj=0;jj<8;jj++){
      unsigned short h = f2bf(xv[jj]);
      bh[jj] = (short)h;
      bl[jj] = (short)f2bf(xv[jj] - bf2f(h));
    }
    unsigned* Yrow = Yp + (size_t)n*1024;
    for (int grp=0; grp<4; grp++){
      int jt_g0 = jhalf*64 + grp*16;
      int kpg = jhalf*4 + grp;
      uint4 Q[2][4];
      #pragma unroll
      for (int a=0; a<4; a++){
        #pragma unroll
        for (int b=0; b<2; b++){
          int jt_lo = jt_g0 + 4*a + b;
          int jt_hi = jt_lo + 2;
          s8v AhL = *(const s8v*)(W3h + (size_t)(jt_lo*64 + lane)*8);
          s8v AlL = *(const s8v*)(W3l + (size_t)(jt_lo*64 + lane)*8);
          f4v aL = __builtin_amdgcn_mfma_f32_16x16x32_bf16(AhL, bl, fz, 0, 0, 0);
          aL = __builtin_amdgcn_mfma_f32_16x16x32_bf16(AlL, bh, aL, 0, 0, 0);
          aL = __builtin_amdgcn_mfma_f32_16x16x32_bf16(AhL, bh, aL, 0, 0, 0);
          s8v AhH = *(const s8v*)(W3h + (size_t)(jt_hi*64 + lane)*8);
          s8v AlH = *(const s8v*)(W3l + (size_t)(jt_hi*64 + lane)*8);
          f4v aH = __builtin_amdgcn_mfma_f32_16x16x32_bf16(AhH, bl, fz, 0, 0, 0);
          aH = __builtin_amdgcn_mfma_f32_16x16x32_bf16(AlH, bh, aH, 0, 0, 0);
          aH = __builtin_amdgcn_mfma_f32_16x16x32_bf16(AhH, bh, aH, 0, 0, 0);
          #pragma unroll
          for (int r=0;r<4;r++){
            unsigned pv = pkh(aL[r], aH[r]);
            if (a==0) Q[b][r].x = pv;
            else if (a==1) Q[b][r].y = pv;
            else if (a==2) Q[b][r].z = pv;
            else Q[b][r].w = pv;
          }
        }
      }
      #pragma unroll
      for (int b=0;b<2;b++)
        #pragma unroll
        for (int r=0;r<4;r++){
          int o = b*16 + g*4 + r;
          *(uint4*)(Yrow + kpg*128 + o*4) = Q[b][r];
        }
    }
  } else {
    __shared__ __align__(16) float sx[8][32];
    int b2 = bid - 938;
    int oo = tid & 31, nn = tid >> 5;
    float wb[32], wr[32];
    #pragma unroll
    for (int f=0;f<32;f++){ wb[f]=be3[f*32+oo]; wr[f]=Wroot[f*32+oo]; }
    float bcv = bc1[oo];
    int per = (1250 + 63)/64;
    int g0 = b2*per, g1 = min(g0+per, 1250);
    for (int gi=g0; gi<g1; gi++){
      int nb = gi*8;
      __syncthreads();
      sx[tid>>5][tid&31] = x[(size_t)nb*32 + tid];
      __syncthreads();
      float a1=0.f, a2=0.f;
      #pragma unroll
      for (int f4=0;f4<8;f4++){
        float4 xvv = *(const float4*)(&sx[nn][f4*4]);
        a1 += xvv.x*wb[f4*4+0]+xvv.y*wb[f4*4+1]+xvv.z*wb[f4*4+2]+xvv.w*wb[f4*4+3];
        a2 += xvv.x*wr[f4*4+0]+xvv.y*wr[f4*4+1]+xvv.z*wr[f4*4+2]+xvv.w*wr[f4*4+3];
      }
      xb[(size_t)(nb+nn)*32+oo] = a1;
      agg[(size_t)(nb+nn)*32+oo] = a2 + bcv;
    }
  }
}

// =============== mega-kernel phases (cross-phase outputs via system-scope stores) ===============

static __device__ void msg_phase(const unsigned* __restrict__ Yp,
    const float* __restrict__ xb, const unsigned* __restrict__ t2b,
    const int* __restrict__ rp_src, const int* __restrict__ dstp,
    float* __restrict__ agg){
  int tid=threadIdx.x, w=tid>>6, lane=tid&63;
  int c = lane&15, g = lane>>4;
  int gw = blockIdx.x*4 + w;
  const f4v fz = {0.f,0.f,0.f,0.f};
  for (int n=gw; n<NN; n+=NBLK*4){
    int beg=rp_src[n], end=rp_src[n+1];
    if (beg==end) continue;
    const unsigned* Yr = Yp + (size_t)n*1024;
    h8v B[2][2];
    #pragma unroll
    for (int kt=0;kt<2;kt++)
      #pragma unroll
      for (int jn=0;jn<2;jn++)
        B[kt][jn] = __builtin_bit_cast(h8v, *(const uint4*)(Yr + (kt*4+g)*128 + (jn*16+c)*4));
    float xq0 = xb[(size_t)n*32 + c];
    float xq1 = xb[(size_t)n*32 + c + 16];
    for (int eb=beg; eb<end; eb+=16){
      const unsigned* tr = t2b + (size_t)(eb + c)*32;
      h8v A0 = __builtin_bit_cast(h8v, *(const uint4*)(tr + g*4));
      h8v A1 = __builtin_bit_cast(h8v, *(const uint4*)(tr + 16 + g*4));
      f4v acc0 = __builtin_amdgcn_mfma_f32_16x16x32_f16(A0, B[0][0], fz, 0, 0, 0);
      acc0 = __builtin_amdgcn_mfma_f32_16x16x32_f16(A1, B[1][0], acc0, 0, 0, 0);
      f4v acc1 = __builtin_amdgcn_mfma_f32_16x16x32_f16(A0, B[0][1], fz, 0, 0, 0);
      acc1 = __builtin_amdgcn_mfma_f32_16x16x32_f16(A1, B[1][1], acc1, 0, 0, 0);
      #pragma unroll
      for (int r=0;r<4;r++){
        int p = eb + g*4 + r;
        if (p < end){
          int d = dstp[p];
          float* ap = agg + (size_t)d*32;
          unsafeAtomicAdd(ap + c,      acc0[r] + xq0);
          unsafeAtomicAdd(ap + c + 16, acc1[r] + xq1);
        }
      }
    }
  }
}

static __device__ void stats_phase(const float* __restrict__ buf, int nrows, int ncols,
                                   float* __restrict__ stats, char* smem){
  if (blockIdx.x < 64){
    int tid = threadIdx.x;
    int c  = tid % ncols;
    int r0 = tid / ncols;
    int rp = 256 / ncols;
    float s1=0.f, s2=0.f;
    for (int base=blockIdx.x*rp; base<nrows; base+=64*rp){
      int r = base + r0;
      if (r < nrows){
        float v = buf[(size_t)r*ncols + c];
        s1 += v; s2 += v*v;
      }
    }
    float* A = (float*)smem;
    float* B = A + 256;
    A[tid]=s1; B[tid]=s2; __syncthreads();
    if (tid < ncols){
      float t1=0.f, t2=0.f;
      for (int gg=0; gg<256/ncols; gg++){ t1 += A[gg*ncols+tid]; t2 += B[gg*ncols+tid]; }
      atomicAdd(&stats[tid], t1);
      atomicAdd(&stats[ncols+tid], t2);
    }
  }
}

template<int FIN, int FOUT>
static __device__ void linear_phase(const float* __restrict__ raw,
    const float* __restrict__ stats, const float* __restrict__ W,
    const float* __restrict__ avs, const float* __restrict__ avd,
    unsigned short* __restrict__ hWh, float* __restrict__ sc_s, float* __restrict__ sc_d,
    char* smem){
  float* sW = (float*)smem;
  float* sA = sW + FIN*FOUT;
  float* sD = sA + FOUT;
  float* sScale = sD + FOUT;
  float* sShift = sScale + FIN;
  float* sIn = sShift + FIN;   // [4][FIN]
  int tid = threadIdx.x;
  for (int i=tid;i<FIN*FOUT;i+=256) sW[i]=W[i];
  if (tid<FOUT){ sA[tid]=avs[tid]; sD[tid]=avd[tid]; }
  if (tid<FIN){
    float m = stats[tid]*(1.f/NN);
    float v = stats[FIN+tid]*(1.f/NN) - m*m;
    float s = rsqrtf(v + 1e-5f);
    sScale[tid]=s; sShift[tid]=-m*s;
  }
  __syncthreads();
  int wave=tid>>6, lane=tid&63;
  for (int nb = blockIdx.x*4; nb < NN; nb += NBLK*4){
    int n = nb + wave;
    bool act = n < NN;
    if (act){
      for (int ff=lane; ff<FIN; ff+=64){
        float vv = raw[(size_t)n*FIN+ff]*sScale[ff]+sShift[ff];
        sIn[wave*FIN+ff] = fmaxf(vv, 0.f);
      }
    }
    __syncthreads();
    if (act){
      float out0=0.f, out1=0.f;
      #pragma unroll
      for (int ff=0; ff<FIN; ff++){
        float xv = sIn[wave*FIN+ff];
        out0 += xv*sW[ff*FOUT+lane];
        if constexpr (FOUT > 64) out1 += xv*sW[ff*FOUT+lane+64];
      }
      // pair lanes -> 4B system stores (bypass L2)
      unsigned short m0 = f2h(out0);
      unsigned n0 = (unsigned)__shfl_down((int)m0, 1);
      if ((lane & 1) == 0)
        stu((unsigned*)(hWh + (size_t)n*FOUT + lane), (unsigned)m0 | (n0<<16));
      float ps = out0*sA[lane], pd = out0*sD[lane];
      if constexpr (FOUT > 64){
        unsigned short m1 = f2h(out1);
        unsigned n1 = (unsigned)__shfl_down((int)m1, 1);
        if ((lane & 1) == 0)
          stu((unsigned*)(hWh + (size_t)n*FOUT + lane + 64), (unsigned)m1 | (n1<<16));
        ps += out1*sA[lane+64]; pd += out1*sD[lane+64];
      }
      #pragma unroll
      for (int off=32;off>0;off>>=1){ ps += __shfl_down(ps,off); pd += __shfl_down(pd,off); }
      if (lane==0){ stf(&sc_s[n], ps); stf(&sc_d[n], pd); }
    }
    __syncthreads();
  }
}

template<int F>
static __device__ void attn_phase(const unsigned short* __restrict__ hWh,
    const float* __restrict__ sc_s, const float* __restrict__ sc_d,
    const int* __restrict__ rp_dst, const int* __restrict__ srcd,
    const float* __restrict__ bias, float* __restrict__ outraw){
  int tid=threadIdx.x, w=tid>>6, lane=tid&63;
  int gw = blockIdx.x*4 + w;
  for (int n=gw; n<NN; n+=NBLK*4){
    int beg=rp_dst[n], end=rp_dst[n+1];
    float scd = sc_d[n];
    float M=-3e38f, S=0.f, acc0=0.f, acc1=0.f;
    for (int base=beg; base<end; base+=64){
      int nb = min(64, end-base);
      float sc=-3e38f; int si=0;
      if (lane<nb){ si = srcd[base+lane]; sc = lrelu(sc_s[si]+scd); }
      float cm=sc;
      #pragma unroll
      for (int off=32;off>0;off>>=1) cm = fmaxf(cm, __shfl_xor(cm,off));
      float Mn = fmaxf(M, cm);
      float p = (lane<nb) ? __expf(sc-Mn) : 0.f;
      float ps=p;
      #pragma unroll
      for (int off=32;off>0;off>>=1) ps += __shfl_xor(ps,off);
      float scale = __expf(M-Mn);
      S = S*scale + ps;
      acc0*=scale; acc1*=scale;
      int jj=0;
      for (; jj+4<=nb; jj+=4){
        float p0=__shfl(p,jj), p1=__shfl(p,jj+1), p2=__shfl(p,jj+2), p3=__shfl(p,jj+3);
        int   q0=__shfl(si,jj), q1=__shfl(si,jj+1), q2=__shfl(si,jj+2), q3=__shfl(si,jj+3);
        if constexpr (F==128){
          unsigned u0 = *(const unsigned*)(hWh + (size_t)q0*128 + 2*lane);
          unsigned u1 = *(const unsigned*)(hWh + (size_t)q1*128 + 2*lane);
          unsigned u2 = *(const unsigned*)(hWh + (size_t)q2*128 + 2*lane);
          unsigned u3 = *(const unsigned*)(hWh + (size_t)q3*128 + 2*lane);
          acc0 += p0*h2f((unsigned short)(u0&0xffffu)); acc1 += p0*h2f((unsigned short)(u0>>16));
          acc0 += p1*h2f((unsigned short)(u1&0xffffu)); acc1 += p1*h2f((unsigned short)(u1>>16));
          acc0 += p2*h2f((unsigned short)(u2&0xffffu)); acc1 += p2*h2f((unsigned short)(u2>>16));
          acc0 += p3*h2f((unsigned short)(u3&0xffffu)); acc1 += p3*h2f((unsigned short)(u3>>16));
        } else {
          float v0 = h2f(hWh[(size_t)q0*64+lane]);
          float v1 = h2f(hWh[(size_t)q1*64+lane]);
          float v2 = h2f(hWh[(size_t)q2*64+lane]);
          float v3 = h2f(hWh[(size_t)q3*64+lane]);
          acc0 += p0*v0 + p1*v1 + p2*v2 + p3*v3;
        }
      }
      for (; jj<nb; jj++){
        float pj=__shfl(p,jj); int qj=__shfl(si,jj);
        if constexpr (F==128){
          unsigned u = *(const unsigned*)(hWh + (size_t)qj*128 + 2*lane);
          acc0 += pj*h2f((unsigned short)(u&0xffffu));
          acc1 += pj*h2f((unsigned short)(u>>16));
        } else {
          acc0 += pj*h2f(hWh[(size_t)qj*64+lane]);
        }
      }
      M = Mn;
    }
    float sself = lrelu(sc_s[n]+scd);
    float Mn = fmaxf(M, sself);
    float scale = __expf(M-Mn);
    float pself = __expf(sself-Mn);
    S = S*scale + pself;
    acc0*=scale; acc1*=scale;
    float inv = 1.f/(S+1e-16f);
    if constexpr (F==128){
      unsigned u = *(const unsigned*)(hWh + (size_t)n*128 + 2*lane);
      acc0 += pself*h2f((unsigned short)(u&0xffffu));
      acc1 += pself*h2f((unsigned short)(u>>16));
      float ox = acc0*inv + bias[2*lane];
      float oy = acc1*inv + bias[2*lane+1];
      stf2(outraw + (size_t)n*128 + 2*lane, ox, oy);
    } else {
      acc0 += pself*h2f(hWh[(size_t)n*64+lane]);
      stf(outraw + (size_t)n*64 + lane, acc0*inv + bias[lane]);
    }
  }
}

static __device__ void poolhead1_phase(const float* __restrict__ h2raw,
    const float* __restrict__ stats, const int* __restrict__ starts,
    const float* __restrict__ Wf1, const float* __restrict__ bf1,
    float* __restrict__ g1, float* __restrict__ statsH1, char* smem){
  if (blockIdx.x >= NGB) return;
  float* sc = (float*)smem;          // 128
  float* sh = sc + 128;              // 128
  float* red = sh + 128;             // 256
  float* sg = red + 256;             // 128
  int b=blockIdx.x, t=threadIdx.x;
  if (t<128){
    float m = stats[t]*(1.f/NN);
    float v = stats[128+t]*(1.f/NN) - m*m;
    float s = rsqrtf(v+1e-5f);
    sc[t]=s; sh[t]=-m*s;
  }
  __syncthreads();
  int s0=starts[b], s1=starts[b+1];
  int f=t&127, half=t>>7;
  float acc=0.f;
  for (int n=s0+half;n<s1;n+=2){
    float v = h2raw[(size_t)n*128+f]*sc[f]+sh[f];
    acc += fmaxf(v,0.f);
  }
  red[t]=acc; __syncthreads();
  if (half==0){
    int cnt = s1-s0;
    sg[f] = (red[f]+red[128+f]) / fmaxf((float)cnt, 1.f);
  }
  __syncthreads();
  float a = bf1[t];
  #pragma unroll 4
  for (int k=0;k<128;k++) a += sg[k]*Wf1[k*256+t];
  stf(&g1[b*256+t], a);
  atomicAdd(&statsH1[t], a);
  atomicAdd(&statsH1[256+t], a*a);
}

static __device__ void head2_phase(const float* __restrict__ g1,
    const float* __restrict__ stats, const float* __restrict__ Wf2,
    const float* __restrict__ bf2, float* __restrict__ g2, float* __restrict__ statsH2,
    char* smem){
  if (blockIdx.x >= NGB) return;
  float* sin_ = (float*)smem;        // 256
  int r=blockIdx.x, t=threadIdx.x;
  float m = stats[t]*(1.f/NGB);
  float v = stats[256+t]*(1.f/NGB) - m*m;
  float val = (g1[r*256+t]-m)*rsqrtf(v+1e-5f);
  sin_[t]=fmaxf(val,0.f);
  __syncthreads();
  if (t<128){
    float acc=bf2[t];
    #pragma unroll 4
    for (int k=0;k<256;k++) acc += sin_[k]*Wf2[k*128+t];
    stf(&g2[r*128+t], acc);
    atomicAdd(&statsH2[t], acc);
    atomicAdd(&statsH2[128+t], acc*acc);
  }
}

static __device__ void head3_phase(const float* __restrict__ g2,
    const float* __restrict__ stats, const float* __restrict__ Wf3,
    const float* __restrict__ bf3, float* __restrict__ out, char* smem){
  if (blockIdx.x >= NGB) return;
  float* sin_ = (float*)smem;        // 128
  int r=blockIdx.x, t=threadIdx.x;
  if (t<128){
    float m = stats[t]*(1.f/NGB);
    float v = stats[128+t]*(1.f/NGB) - m*m;
    float val = (g2[r*128+t]-m)*rsqrtf(v+1e-5f);
    sin_[t]=fmaxf(val,0.f);
  }
  __syncthreads();
  if (t<64){
    float acc=bf3[t];
    #pragma unroll 4
    for (int k=0;k<128;k++) acc += sin_[k]*Wf3[k*64+t];
    out[r*64+t]=acc;   // final output: visible via kernel-end flush
  }
}

// =============== mega-kernel: msg -> GAT x2 -> pool -> head, fence-free grid barriers ===============
__global__ __launch_bounds__(256, 4) void k_mega(
    const unsigned* __restrict__ Yp, const float* __restrict__ xb, const unsigned* __restrict__ t2b,
    const int* __restrict__ rp_src, const int* __restrict__ dstp, float* __restrict__ agg,
    const int* __restrict__ rp_dst, const int* __restrict__ srcd,
    float* __restrict__ stats0, float* __restrict__ stats1, float* __restrict__ stats2,
    const float* __restrict__ Wg1, const float* __restrict__ as1, const float* __restrict__ ad1, const float* __restrict__ bg1,
    const float* __restrict__ Wg2, const float* __restrict__ as2, const float* __restrict__ ad2, const float* __restrict__ bg2,
    unsigned short* __restrict__ hW1, float* __restrict__ scs1, float* __restrict__ scd1, float* __restrict__ h1,
    unsigned short* __restrict__ hW2, float* __restrict__ scs2, float* __restrict__ scd2, float* __restrict__ h2,
    const int* __restrict__ starts, const float* __restrict__ Wf1, const float* __restrict__ bf1,
    float* __restrict__ g1, float* __restrict__ statsH1,
    const float* __restrict__ Wf2, const float* __restrict__ bf2, float* __restrict__ g2, float* __restrict__ statsH2,
    const float* __restrict__ Wf3, const float* __restrict__ bf3, float* __restrict__ out,
    int* __restrict__ bar){
  __shared__ __align__(16) char smem[35840];   // max phase need: linear<64,128> = 35328 B
  int tgt = NBLK;
  msg_phase(Yp, xb, t2b, rp_src, dstp, agg);
  gridbar(bar, tgt); tgt += NBLK;
  stats_phase(agg, NN, 32, stats0, smem);
  gridbar(bar, tgt); tgt += NBLK;
  linear_phase<32,64>(agg, stats0, Wg1, as1, ad1, hW1, scs1, scd1, smem);
  gridbar(bar, tgt); tgt += NBLK;
  attn_phase<64>(hW1, scs1, scd1, rp_dst, srcd, bg1, h1);
  gridbar(bar, tgt); tgt += NBLK;
  stats_phase(h1, NN, 64, stats1, smem);
  gridbar(bar, tgt); tgt += NBLK;
  linear_phase<64,128>(h1, stats1, Wg2, as2, ad2, hW2, scs2, scd2, smem);
  gridbar(bar, tgt); tgt += NBLK;
  attn_phase<128>(hW2, scs2, scd2, rp_dst, srcd, bg2, h2);
  gridbar(bar, tgt); tgt += NBLK;
  stats_phase(h2, NN, 128, stats2, smem);
  gridbar(bar, tgt); tgt += NBLK;
  poolhead1_phase(h2, stats2, starts, Wf1, bf1, g1, statsH1, smem);
  gridbar(bar, tgt); tgt += NBLK;
  head2_phase(g1, statsH1, Wf2, bf2, g2, statsH2, smem);
  gridbar(bar, tgt); tgt += NBLK;
  head3_phase(g2, statsH2, Wf3, bf3, out, smem);
}

extern "C" void kernel_launch(void* const* d_in, const int* in_sizes, int n_in,
                              void* d_out, int out_size, void* d_ws, size_t ws_size,
                              hipStream_t stream){
  const float* x    = (const float*)d_in[0];
  const int*   ei   = (const int*)d_in[1];
  const float* ea   = (const float*)d_in[2];
  const int*   batch= (const int*)d_in[3];
  const float* We1=(const float*)d_in[4];  const float* be1=(const float*)d_in[5];
  const float* We2=(const float*)d_in[6];  const float* be2=(const float*)d_in[7];
  const float* We3=(const float*)d_in[8];  const float* be3=(const float*)d_in[9];
  const float* Wroot=(const float*)d_in[10]; const float* bc1=(const float*)d_in[11];
  const float* Wg1=(const float*)d_in[12]; const float* as1=(const float*)d_in[13];
  const float* ad1=(const float*)d_in[14]; const float* bg1=(const float*)d_in[15];
  const float* Wg2=(const float*)d_in[16]; const float* as2=(const float*)d_in[17];
  const float* ad2=(const float*)d_in[18]; const float* bg2=(const float*)d_in[19];
  const float* Wf1=(const float*)d_in[20]; const float* bf1=(const float*)d_in[21];
  const float* Wf2=(const float*)d_in[22]; const float* bf2=(const float*)d_in[23];
  const float* Wf3=(const float*)d_in[24]; const float* bf3=(const float*)d_in[25];
  (void)in_sizes; (void)n_in; (void)out_size; (void)ws_size;
  float* out = (float*)d_out;
  char* ws = (char*)d_ws;
  const int* srcA = ei;
  const int* dstA = ei + NE;

  size_t off = 0;
  auto take = [&](size_t bytes)->size_t{ size_t r = off; off += (bytes + 255) & ~(size_t)255; return r; };
  // zero region (memset in-graph -> re-zeroed every replay, incl. barrier counter)
  size_t o_deg_src = take(NN*4), o_deg_dst = take(NN*4);
  size_t o_fill_src = take(NN*4), o_fill_dst = take(NN*4);
  size_t o_stats0 = take(2*32*4), o_stats1 = take(2*64*4), o_stats2 = take(2*128*4);
  size_t o_statsH1 = take(2*256*4), o_statsH2 = take(2*128*4);
  size_t o_bar = take(256);
  size_t zero_bytes = off;
  // rest
  size_t o_rp_src = take((NN+1)*4), o_rp_dst = take((NN+1)*4);
  size_t o_pos_src = take((size_t)NE*4);
  size_t o_dstp = take((size_t)NE*4);
  size_t o_srcd = take((size_t)NE*4);
  size_t o_starts = take((NGB+1)*4);
  size_t o_W1p = take(4096*2);
  size_t o_W2p = take(8192*2);
  size_t o_W3h = take((size_t)128*64*8*2);
  size_t o_W3l = take((size_t)128*64*8*2);
  size_t o_t2b = take((size_t)(NE+16)*32*4);       // f16 k-pairs, pad for MFMA tail
  size_t o_Yp  = take((size_t)NN*1024*4);          // f16 k-pairs, kpg-major
  size_t o_xb  = take((size_t)NN*32*4);
  size_t o_agg = take((size_t)NN*32*4);
  size_t o_hW1 = take((size_t)NN*64*2);
  size_t o_scs1 = take(NN*4), o_scd1 = take(NN*4);
  size_t o_h1  = take((size_t)NN*64*4);
  size_t o_hW2 = take((size_t)NN*128*2);
  size_t o_scs2 = take(NN*4), o_scd2 = take(NN*4);
  size_t o_h2  = take((size_t)NN*128*4);
  size_t o_g1  = take(NGB*256*4);
  size_t o_g2  = take(NGB*128*4);

  #define WF(o) ((float*)(ws + (o)))
  #define WI(o) ((int*)(ws + (o)))
  #define WU(o) ((unsigned short*)(ws + (o)))
  #define WW(o) ((unsigned*)(ws + (o)))

  (void)hipMemsetAsync(ws, 0, zero_bytes, stream);
  k_prep<<<625,256,0,stream>>>(srcA,dstA,batch,We1,be1,We2,We3,
                               WI(o_deg_src),WI(o_deg_dst),WI(o_starts),
                               WU(o_W1p),WU(o_W2p),WU(o_W3h),WU(o_W3l));
  k_scan<<<2,1024,0,stream>>>(WI(o_deg_src),WI(o_deg_dst),WI(o_rp_src),WI(o_rp_dst));
  k_fill<<<625,256,0,stream>>>(srcA,dstA,WI(o_rp_src),WI(o_rp_dst),
                               WI(o_fill_src),WI(o_fill_dst),
                               WI(o_pos_src),WI(o_dstp),WI(o_srcd));
  k_big<<<1002,256,0,stream>>>(ea,WU(o_W1p),WU(o_W2p),be2,WI(o_pos_src),WW(o_t2b),
                               x,WU(o_W3h),WU(o_W3l),WW(o_Yp),
                               be3,Wroot,bc1,WF(o_xb),WF(o_agg));
  k_mega<<<NBLK,256,0,stream>>>(WW(o_Yp),WF(o_xb),WW(o_t2b),
                                WI(o_rp_src),WI(o_dstp),WF(o_agg),
                                WI(o_rp_dst),WI(o_srcd),
                                WF(o_stats0),WF(o_stats1),WF(o_stats2),
                                Wg1,as1,ad1,bg1, Wg2,as2,ad2,bg2,
                                WU(o_hW1),WF(o_scs1),WF(o_scd1),WF(o_h1),
                                WU(o_hW2),WF(o_scs2),WF(o_scd2),WF(o_h2),
                                WI(o_starts),Wf1,bf1,WF(o_g1),WF(o_statsH1),
                                Wf2,bf2,WF(o_g2),WF(o_statsH2),
                                Wf3,bf3,out,
                                WI(o_bar));
}

// Round 15
// 263.289 us; speedup vs baseline: 4.7261x; 2.5196x over previous
//
#include <hip/hip_runtime.h>

#define NN 10000      // nodes
#define NE 160000     // edges
#define NGB 100       // graphs

typedef __attribute__((ext_vector_type(8))) short s8v;     // 8 x bf16
typedef __attribute__((ext_vector_type(4))) float f4v;     // MFMA accumulator
typedef __attribute__((ext_vector_type(2))) _Float16 h2v;  // half2
typedef __attribute__((ext_vector_type(8))) _Float16 h8v;  // 8 x f16 (MFMA operand)

static __device__ __forceinline__ float lrelu(float v){ return v > 0.f ? v : 0.2f*v; }
static __device__ __forceinline__ unsigned short f2bf(float f){
  unsigned u = __float_as_uint(f);
  u += 0x7fffu + ((u >> 16) & 1u);
  return (unsigned short)(u >> 16);
}
static __device__ __forceinline__ float bf2f(unsigned short h){
  return __uint_as_float(((unsigned)h) << 16);
}
static __device__ __forceinline__ unsigned pkh(float a, float b){
  auto h = __builtin_amdgcn_cvt_pkrtz(a, b);
  return __builtin_bit_cast(unsigned, h);
}
static __device__ __forceinline__ unsigned short f2h(float f){
  _Float16 h = (_Float16)f;
  return __builtin_bit_cast(unsigned short, h);
}
static __device__ __forceinline__ float h2f(unsigned short u){
  return (float)__builtin_bit_cast(_Float16, u);
}

// ---------------- prep: degrees + graph bounds + ALL weight packs ----------------
__global__ __launch_bounds__(256) void k_prep(const int* __restrict__ src, const int* __restrict__ dst,
    const int* __restrict__ batch,
    const float* __restrict__ We1, const float* __restrict__ be1,
    const float* __restrict__ We2, const float* __restrict__ We3,
    int* deg_src, int* deg_dst, int* starts,
    unsigned short* __restrict__ W1p, unsigned short* __restrict__ W2p,
    unsigned short* __restrict__ W3h, unsigned short* __restrict__ W3l){
  int i = blockIdx.x*256 + threadIdx.x;
  if (i < NE){ atomicAdd(&deg_src[src[i]],1); atomicAdd(&deg_dst[dst[i]],1); }
  if (i <= NN){
    int cur  = (i==NN) ? NGB : batch[i];
    int prev = (i==0)  ? -1  : batch[i-1];
    for (int b=prev+1; b<=cur; b++) if (b<=NGB) starts[b]=i;
  }
  int tid = threadIdx.x;
  if (blockIdx.x == 32){
    for (int idx=tid; idx<512; idx+=256){
      int j=idx>>6, l=idx&63, col=l&15, g=l>>4;
      int out = j*16+col;
      #pragma unroll
      for (int jj=0;jj<8;jj++){
        int k = g*8+jj;
        float v = (k<16) ? We1[k*128+out] : (k==16 ? be1[out] : 0.f);
        W1p[idx*8+jj] = f2bf(v);
      }
    }
    for (int idx=tid; idx<1024; idx+=256){
      int ft=idx>>6, l=idx&63, col=l&15, g=l>>4;
      int t=ft>>2, jo=ft&3;
      int out = jo*16+col;
      #pragma unroll
      for (int jj=0;jj<8;jj++){
        int k = t*32+g*8+jj;
        W2p[idx*8+jj] = f2bf(We2[k*64+out]);
      }
    }
  } else if (blockIdx.x < 32){
    int idx = blockIdx.x*256 + tid;   // [0, 8192)
    int jt = idx>>6, l = idx&63;
    int j = jt*16 + (l&15);
    int f0 = (l>>4)*8;
    int k = j>>5, o = j&31;
    #pragma unroll
    for (int jj=0;jj<8;jj++){
      float v = We3[(size_t)k*1024 + (size_t)(f0+jj)*32 + o];
      unsigned short h = f2bf(v);
      float r = v - bf2f(h);
      W3h[(size_t)idx*8+jj] = h;
      W3l[(size_t)idx*8+jj] = f2bf(r);
    }
  }
}

__global__ __launch_bounds__(1024) void k_scan(const int* __restrict__ deg_src, const int* __restrict__ deg_dst,
                                               int* rp_src, int* rp_dst){
  const int* deg = (blockIdx.x==0) ? deg_src : deg_dst;
  int* rp = (blockIdx.x==0) ? rp_src : rp_dst;
  __shared__ int part[1024];
  int tid = threadIdx.x;
  const int per = (NN + 1023)/1024;   // 10
  int base = tid*per;
  int s = 0;
  for (int i=0;i<per;i++){ int idx=base+i; if (idx<NN) s += deg[idx]; }
  part[tid]=s; __syncthreads();
  for (int off=1; off<1024; off<<=1){
    int v = part[tid];
    int add = (tid>=off) ? part[tid-off] : 0;
    __syncthreads();
    part[tid] = v + add;
    __syncthreads();
  }
  int run = (tid==0) ? 0 : part[tid-1];
  for (int i=0;i<per;i++){ int idx=base+i; if (idx<NN){ rp[idx]=run; run += deg[idx]; } }
  if (tid==1023) rp[NN] = part[1023];
}

__global__ __launch_bounds__(256) void k_fill(const int* __restrict__ src, const int* __restrict__ dst,
                       const int* __restrict__ rp_src, const int* __restrict__ rp_dst,
                       int* fill_src, int* fill_dst, int* pos_src, int* dstp, int* srcd){
  int i = blockIdx.x*256 + threadIdx.x;
  if (i < NE){
    int s=src[i], d=dst[i];
    int p=rp_src[s]+atomicAdd(&fill_src[s],1); pos_src[i]=p; dstp[p]=d;
    int q=rp_dst[d]+atomicAdd(&fill_dst[d],1); srcd[q]=s;
  }
}

// ---------------- fused: edge-MLP (blocks 0..624) | Y (625..937) | xb/agg (938..1001) ----------------
__global__ __launch_bounds__(256) void k_big(const float* __restrict__ ea,
    const unsigned short* __restrict__ W1p, const unsigned short* __restrict__ W2p,
    const float* __restrict__ be2, const int* __restrict__ pos_src, unsigned* __restrict__ t2b,
    const float* __restrict__ x,
    const unsigned short* __restrict__ W3h, const unsigned short* __restrict__ W3l,
    unsigned* __restrict__ Yp,
    const float* __restrict__ be3, const float* __restrict__ Wroot, const float* __restrict__ bc1,
    float* __restrict__ xb, float* __restrict__ agg){
  __shared__ unsigned short st1[4*2048];
  int bid = blockIdx.x;
  int tid=threadIdx.x, wave=tid>>6, lane=tid&63;
  const f4v fz = {0.f,0.f,0.f,0.f};
  if (bid < 625){
    int c = lane&15, g = lane>>4;
    s8v w1f[8], w2f[16];
    #pragma unroll
    for (int j=0;j<8;j++)  w1f[j] = *(const s8v*)(W1p + (size_t)(j*64+lane)*8);
    #pragma unroll
    for (int q=0;q<16;q++) w2f[q] = *(const s8v*)(W2p + (size_t)(q*64+lane)*8);
    float be2v[16];
    #pragma unroll
    for (int jo=0;jo<4;jo++)
      #pragma unroll
      for (int r=0;r<4;r++) be2v[jo*4+r] = be2[jo*16+g*4+r];
    char* myld = (char*)(st1 + wave*2048);
    for (int base = bid*64; base < NE; base += 625*64){
      int e0 = base + wave*16;
      s8v eaf = {0,0,0,0,0,0,0,0};
      if (g < 2){
        const float* p = ea + (size_t)(e0+c)*16 + g*8;
        float4 a = *(const float4*)p;
        float4 b = *(const float4*)(p+4);
        eaf[0]=(short)f2bf(a.x); eaf[1]=(short)f2bf(a.y); eaf[2]=(short)f2bf(a.z); eaf[3]=(short)f2bf(a.w);
        eaf[4]=(short)f2bf(b.x); eaf[5]=(short)f2bf(b.y); eaf[6]=(short)f2bf(b.z); eaf[7]=(short)f2bf(b.w);
      } else if (g == 2){
        eaf[0] = (short)0x3f80;
      }
      f4v acc1[8];
      #pragma unroll
      for (int j=0;j<8;j++)
        acc1[j] = __builtin_amdgcn_mfma_f32_16x16x32_bf16(w1f[j], eaf, fz, 0, 0, 0);
      #pragma unroll
      for (int j=0;j<8;j++){
        unsigned lo = (unsigned)f2bf(fmaxf(acc1[j][0],0.f)) | ((unsigned)f2bf(fmaxf(acc1[j][1],0.f))<<16);
        unsigned hi = (unsigned)f2bf(fmaxf(acc1[j][2],0.f)) | ((unsigned)f2bf(fmaxf(acc1[j][3],0.f))<<16);
        unsigned off = (unsigned)(c*256 + ((j*32 + g*8) ^ (c<<4)));
        *(uint2*)(myld + off) = make_uint2(lo, hi);
      }
      __syncthreads();
      f4v acc2[4];
      #pragma unroll
      for (int jo=0;jo<4;jo++) acc2[jo] = fz;
      #pragma unroll
      for (int t=0;t<4;t++){
        unsigned off = (unsigned)(c*256 + ((t*64 + g*16) ^ (c<<4)));
        s8v b2 = *(const s8v*)(myld + off);
        #pragma unroll
        for (int jo=0;jo<4;jo++)
          acc2[jo] = __builtin_amdgcn_mfma_f32_16x16x32_bf16(w2f[t*4+jo], b2, acc2[jo], 0, 0, 0);
      }
      int pos = pos_src[e0+c];
      unsigned* orow = t2b + (size_t)pos*32;
      #pragma unroll
      for (int jo=0;jo<4;jo++){
        float v0 = fmaxf(acc2[jo][0] + be2v[jo*4+0], 0.f);
        float v1 = fmaxf(acc2[jo][1] + be2v[jo*4+1], 0.f);
        float v2 = fmaxf(acc2[jo][2] + be2v[jo*4+2], 0.f);
        float v3 = fmaxf(acc2[jo][3] + be2v[jo*4+3], 0.f);
        *(uint2*)(orow + jo*8 + g*2) = make_uint2(pkh(v0,v1), pkh(v2,v3));
      }
      __syncthreads();
    }
  } else if (bid < 938){
    int c = lane&15, g = lane>>4;
    int tile = (bid-625)*2 + (wave>>1);
    if (tile >= 625) return;
    int jhalf = wave&1;
    int n = tile*16 + c;
    const float* xr = x + (size_t)n*32 + g*8;
    float4 xa = *(const float4*)xr;
    float4 xc = *(const float4*)(xr+4);
    float xv[8] = {xa.x,xa.y,xa.z,xa.w,xc.x,xc.y,xc.z,xc.w};
    s8v bh, bl;
    #pragma unroll
    for (int jj=0;jj<8;jj++){
      unsigned short h = f2bf(xv[jj]);
      bh[jj] = (short)h;
      bl[jj] = (short)f2bf(xv[jj] - bf2f(h));
    }
    unsigned* Yrow = Yp + (size_t)n*1024;
    for (int grp=0; grp<4; grp++){
      int jt_g0 = jhalf*64 + grp*16;
      int kpg = jhalf*4 + grp;
      uint4 Q[2][4];
      #pragma unroll
      for (int a=0; a<4; a++){
        #pragma unroll
        for (int b=0; b<2; b++){
          int jt_lo = jt_g0 + 4*a + b;
          int jt_hi = jt_lo + 2;
          s8v AhL = *(const s8v*)(W3h + (size_t)(jt_lo*64 + lane)*8);
          s8v AlL = *(const s8v*)(W3l + (size_t)(jt_lo*64 + lane)*8);
          f4v aL = __builtin_amdgcn_mfma_f32_16x16x32_bf16(AhL, bl, fz, 0, 0, 0);
          aL = __builtin_amdgcn_mfma_f32_16x16x32_bf16(AlL, bh, aL, 0, 0, 0);
          aL = __builtin_amdgcn_mfma_f32_16x16x32_bf16(AhL, bh, aL, 0, 0, 0);
          s8v AhH = *(const s8v*)(W3h + (size_t)(jt_hi*64 + lane)*8);
          s8v AlH = *(const s8v*)(W3l + (size_t)(jt_hi*64 + lane)*8);
          f4v aH = __builtin_amdgcn_mfma_f32_16x16x32_bf16(AhH, bl, fz, 0, 0, 0);
          aH = __builtin_amdgcn_mfma_f32_16x16x32_bf16(AlH, bh, aH, 0, 0, 0);
          aH = __builtin_amdgcn_mfma_f32_16x16x32_bf16(AhH, bh, aH, 0, 0, 0);
          #pragma unroll
          for (int r=0;r<4;r++){
            unsigned pv = pkh(aL[r], aH[r]);
            if (a==0) Q[b][r].x = pv;
            else if (a==1) Q[b][r].y = pv;
            else if (a==2) Q[b][r].z = pv;
            else Q[b][r].w = pv;
          }
        }
      }
      #pragma unroll
      for (int b=0;b<2;b++)
        #pragma unroll
        for (int r=0;r<4;r++){
          int o = b*16 + g*4 + r;
          *(uint4*)(Yrow + kpg*128 + o*4) = Q[b][r];
        }
    }
  } else {
    __shared__ __align__(16) float sx[8][32];
    int b2 = bid - 938;
    int oo = tid & 31, nn = tid >> 5;
    float wb[32], wr[32];
    #pragma unroll
    for (int f=0;f<32;f++){ wb[f]=be3[f*32+oo]; wr[f]=Wroot[f*32+oo]; }
    float bcv = bc1[oo];
    int per = (1250 + 63)/64;
    int g0 = b2*per, g1 = min(g0+per, 1250);
    for (int gi=g0; gi<g1; gi++){
      int nb = gi*8;
      __syncthreads();
      sx[tid>>5][tid&31] = x[(size_t)nb*32 + tid];
      __syncthreads();
      float a1=0.f, a2=0.f;
      #pragma unroll
      for (int f4=0;f4<8;f4++){
        float4 xvv = *(const float4*)(&sx[nn][f4*4]);
        a1 += xvv.x*wb[f4*4+0]+xvv.y*wb[f4*4+1]+xvv.z*wb[f4*4+2]+xvv.w*wb[f4*4+3];
        a2 += xvv.x*wr[f4*4+0]+xvv.y*wr[f4*4+1]+xvv.z*wr[f4*4+2]+xvv.w*wr[f4*4+3];
      }
      xb[(size_t)(nb+nn)*32+oo] = a1;
      agg[(size_t)(nb+nn)*32+oo] = a2 + bcv;
    }
  }
}

// ---------------- msg+aggregate via MFMA f16 ----------------
__global__ __launch_bounds__(256) void k_msg4(const unsigned* __restrict__ Yp,
    const float* __restrict__ xb, const unsigned* __restrict__ t2b,
    const int* __restrict__ rp_src, const int* __restrict__ dstp,
    float* __restrict__ agg){
  int tid=threadIdx.x, w=tid>>6, lane=tid&63;
  int c = lane&15, g = lane>>4;
  int gw = blockIdx.x*4 + w, stride = gridDim.x*4;
  const f4v fz = {0.f,0.f,0.f,0.f};
  for (int n=gw; n<NN; n+=stride){
    int beg=rp_src[n], end=rp_src[n+1];
    if (beg==end) continue;
    const unsigned* Yr = Yp + (size_t)n*1024;
    h8v B[2][2];
    #pragma unroll
    for (int kt=0;kt<2;kt++)
      #pragma unroll
      for (int jn=0;jn<2;jn++)
        B[kt][jn] = __builtin_bit_cast(h8v, *(const uint4*)(Yr + (kt*4+g)*128 + (jn*16+c)*4));
    float xq0 = xb[(size_t)n*32 + c];
    float xq1 = xb[(size_t)n*32 + c + 16];
    for (int eb=beg; eb<end; eb+=16){
      const unsigned* tr = t2b + (size_t)(eb + c)*32;
      h8v A0 = __builtin_bit_cast(h8v, *(const uint4*)(tr + g*4));
      h8v A1 = __builtin_bit_cast(h8v, *(const uint4*)(tr + 16 + g*4));
      f4v acc0 = __builtin_amdgcn_mfma_f32_16x16x32_f16(A0, B[0][0], fz, 0, 0, 0);
      acc0 = __builtin_amdgcn_mfma_f32_16x16x32_f16(A1, B[1][0], acc0, 0, 0, 0);
      f4v acc1 = __builtin_amdgcn_mfma_f32_16x16x32_f16(A0, B[0][1], fz, 0, 0, 0);
      acc1 = __builtin_amdgcn_mfma_f32_16x16x32_f16(A1, B[1][1], acc1, 0, 0, 0);
      #pragma unroll
      for (int r=0;r<4;r++){
        int p = eb + g*4 + r;
        if (p < end){
          int d = dstp[p];
          float* ap = agg + (size_t)d*32;
          unsafeAtomicAdd(ap + c,      acc0[r] + xq0);
          unsafeAtomicAdd(ap + c + 16, acc1[r] + xq1);
        }
      }
    }
  }
}

// ---------------- column stats (sum, sumsq); stats pre-zeroed ----------------
__global__ __launch_bounds__(256) void k_stats(const float* __restrict__ buf, int nrows, int ncols,
                                               float* __restrict__ stats){
  int tid = threadIdx.x;
  int c  = tid % ncols;
  int r0 = tid / ncols;
  int rp = 256 / ncols;
  float s1=0.f, s2=0.f;
  for (long long base=(long long)blockIdx.x*rp; base<nrows; base+=(long long)gridDim.x*rp){
    int r = (int)base + r0;
    if (r < nrows){
      float v = buf[(size_t)r*ncols + c];
      s1 += v; s2 += v*v;
    }
  }
  __shared__ float A[256], B[256];
  A[tid]=s1; B[tid]=s2; __syncthreads();
  if (tid < ncols){
    float t1=0.f, t2=0.f;
    for (int gg=0; gg<256/ncols; gg++){ t1 += A[gg*ncols+tid]; t2 += B[gg*ncols+tid]; }
    atomicAdd(&stats[tid], t1);
    atomicAdd(&stats[ncols+tid], t2);
  }
}

// ---------------- GAT linear: in=relu(bn(raw)); hWh=f16(in@W); sc_s,sc_d ----------------
template<int FIN, int FOUT>
__global__ __launch_bounds__(256) void k_gat_linear(const float* __restrict__ raw,
    const float* __restrict__ stats, const float* __restrict__ W,
    const float* __restrict__ avs, const float* __restrict__ avd,
    unsigned short* __restrict__ hWh, float* __restrict__ sc_s, float* __restrict__ sc_d){
  __shared__ float sW[FIN*FOUT];
  __shared__ float sA[FOUT], sD[FOUT];
  __shared__ float sScale[FIN], sShift[FIN];
  __shared__ float sIn[4][FIN];
  int tid = threadIdx.x;
  for (int i=tid;i<FIN*FOUT;i+=256) sW[i]=W[i];
  if (tid<FOUT){ sA[tid]=avs[tid]; sD[tid]=avd[tid]; }
  if (tid<FIN){
    float m = stats[tid]*(1.f/NN);
    float v = stats[FIN+tid]*(1.f/NN) - m*m;
    float s = rsqrtf(v + 1e-5f);
    sScale[tid]=s; sShift[tid]=-m*s;
  }
  __syncthreads();
  int wave=tid>>6, lane=tid&63;
  for (int nb = blockIdx.x*4; nb < NN; nb += gridDim.x*4){
    int n = nb + wave;
    bool act = n < NN;
    if (act){
      for (int ff=lane; ff<FIN; ff+=64){
        float vv = raw[(size_t)n*FIN+ff]*sScale[ff]+sShift[ff];
        sIn[wave][ff] = fmaxf(vv, 0.f);
      }
    }
    __syncthreads();
    if (act){
      float out0=0.f, out1=0.f;
      #pragma unroll
      for (int ff=0; ff<FIN; ff++){
        float xv = sIn[wave][ff];
        out0 += xv*sW[ff*FOUT+lane];
        if constexpr (FOUT > 64) out1 += xv*sW[ff*FOUT+lane+64];
      }
      hWh[(size_t)n*FOUT + lane] = f2h(out0);
      float ps = out0*sA[lane], pd = out0*sD[lane];
      if constexpr (FOUT > 64){
        hWh[(size_t)n*FOUT + lane + 64] = f2h(out1);
        ps += out1*sA[lane+64]; pd += out1*sD[lane+64];
      }
      #pragma unroll
      for (int off=32;off>0;off>>=1){ ps += __shfl_down(ps,off); pd += __shfl_down(pd,off); }
      if (lane==0){ sc_s[n]=ps; sc_d[n]=pd; }
    }
    __syncthreads();
  }
}

// ---------------- GAT attention: 1 wave/node, inline score gather, unrolled hW gathers ----------------
template<int F>
__global__ __launch_bounds__(256) void k_gat_attn5(const unsigned short* __restrict__ hWh,
    const float* __restrict__ sc_s, const float* __restrict__ sc_d,
    const int* __restrict__ rp_dst, const int* __restrict__ srcd,
    const float* __restrict__ bias, float* __restrict__ outraw){
  int tid=threadIdx.x, w=tid>>6, lane=tid&63;
  int gw = blockIdx.x*4 + w, stride = gridDim.x*4;
  for (int n=gw; n<NN; n+=stride){
    int beg=rp_dst[n], end=rp_dst[n+1];
    float scd = sc_d[n];
    float M=-3e38f, S=0.f, acc0=0.f, acc1=0.f;
    for (int base=beg; base<end; base+=64){
      int nb = min(64, end-base);
      float sc=-3e38f; int si=0;
      if (lane<nb){ si = srcd[base+lane]; sc = lrelu(sc_s[si]+scd); }
      float cm=sc;
      #pragma unroll
      for (int off=32;off>0;off>>=1) cm = fmaxf(cm, __shfl_xor(cm,off));
      float Mn = fmaxf(M, cm);
      float p = (lane<nb) ? __expf(sc-Mn) : 0.f;
      float ps=p;
      #pragma unroll
      for (int off=32;off>0;off>>=1) ps += __shfl_xor(ps,off);
      float scale = __expf(M-Mn);
      S = S*scale + ps;
      acc0*=scale; acc1*=scale;
      int jj=0;
      for (; jj+4<=nb; jj+=4){
        float p0=__shfl(p,jj), p1=__shfl(p,jj+1), p2=__shfl(p,jj+2), p3=__shfl(p,jj+3);
        int   q0=__shfl(si,jj), q1=__shfl(si,jj+1), q2=__shfl(si,jj+2), q3=__shfl(si,jj+3);
        if constexpr (F==128){
          unsigned u0 = *(const unsigned*)(hWh + (size_t)q0*128 + 2*lane);
          unsigned u1 = *(const unsigned*)(hWh + (size_t)q1*128 + 2*lane);
          unsigned u2 = *(const unsigned*)(hWh + (size_t)q2*128 + 2*lane);
          unsigned u3 = *(const unsigned*)(hWh + (size_t)q3*128 + 2*lane);
          acc0 += p0*h2f((unsigned short)(u0&0xffffu)); acc1 += p0*h2f((unsigned short)(u0>>16));
          acc0 += p1*h2f((unsigned short)(u1&0xffffu)); acc1 += p1*h2f((unsigned short)(u1>>16));
          acc0 += p2*h2f((unsigned short)(u2&0xffffu)); acc1 += p2*h2f((unsigned short)(u2>>16));
          acc0 += p3*h2f((unsigned short)(u3&0xffffu)); acc1 += p3*h2f((unsigned short)(u3>>16));
        } else {
          float v0 = h2f(hWh[(size_t)q0*64+lane]);
          float v1 = h2f(hWh[(size_t)q1*64+lane]);
          float v2 = h2f(hWh[(size_t)q2*64+lane]);
          float v3 = h2f(hWh[(size_t)q3*64+lane]);
          acc0 += p0*v0 + p1*v1 + p2*v2 + p3*v3;
        }
      }
      for (; jj<nb; jj++){
        float pj=__shfl(p,jj); int qj=__shfl(si,jj);
        if constexpr (F==128){
          unsigned u = *(const unsigned*)(hWh + (size_t)qj*128 + 2*lane);
          acc0 += pj*h2f((unsigned short)(u&0xffffu));
          acc1 += pj*h2f((unsigned short)(u>>16));
        } else {
          acc0 += pj*h2f(hWh[(size_t)qj*64+lane]);
        }
      }
      M = Mn;
    }
    float sself = lrelu(sc_s[n]+scd);
    float Mn = fmaxf(M, sself);
    float scale = __expf(M-Mn);
    float pself = __expf(sself-Mn);
    S = S*scale + pself;
    acc0*=scale; acc1*=scale;
    float inv = 1.f/(S+1e-16f);
    if constexpr (F==128){
      unsigned u = *(const unsigned*)(hWh + (size_t)n*128 + 2*lane);
      acc0 += pself*h2f((unsigned short)(u&0xffffu));
      acc1 += pself*h2f((unsigned short)(u>>16));
      float ox = acc0*inv + bias[2*lane];
      float oy = acc1*inv + bias[2*lane+1];
      *(float2*)(outraw + (size_t)n*128 + 2*lane) = make_float2(ox, oy);
    } else {
      acc0 += pself*h2f(hWh[(size_t)n*64+lane]);
      outraw[(size_t)n*64+lane] = acc0*inv + bias[lane];
    }
  }
}

// ---------------- pool (bn+relu on read) + head1 fused; stats via atomics (100 blocks) ----------------
__global__ __launch_bounds__(256) void k_poolhead1(const float* __restrict__ h2raw,
    const float* __restrict__ stats, const int* __restrict__ starts,
    const float* __restrict__ Wf1, const float* __restrict__ bf1,
    float* __restrict__ g1, float* __restrict__ statsH1){
  __shared__ float sc[128], sh[128], red[256], sg[128];
  int b=blockIdx.x, t=threadIdx.x;
  if (t<128){
    float m = stats[t]*(1.f/NN);
    float v = stats[128+t]*(1.f/NN) - m*m;
    float s = rsqrtf(v+1e-5f);
    sc[t]=s; sh[t]=-m*s;
  }
  __syncthreads();
  int s0=starts[b], s1=starts[b+1];
  int f=t&127, half=t>>7;
  float acc=0.f;
  for (int n=s0+half;n<s1;n+=2){
    float v = h2raw[(size_t)n*128+f]*sc[f]+sh[f];
    acc += fmaxf(v,0.f);
  }
  red[t]=acc; __syncthreads();
  if (half==0){
    int cnt = s1-s0;
    sg[f] = (red[f]+red[128+f]) / fmaxf((float)cnt, 1.f);
  }
  __syncthreads();
  float a = bf1[t];
  #pragma unroll 4
  for (int k=0;k<128;k++) a += sg[k]*Wf1[k*256+t];
  g1[b*256+t]=a;
  atomicAdd(&statsH1[t], a);
  atomicAdd(&statsH1[256+t], a*a);
}

__global__ __launch_bounds__(256) void k_head2(const float* __restrict__ g1,
    const float* __restrict__ stats, const float* __restrict__ Wf2,
    const float* __restrict__ bf2, float* __restrict__ g2, float* __restrict__ statsH2){
  __shared__ float sin_[256];
  int r=blockIdx.x, t=threadIdx.x;
  float m = stats[t]*(1.f/NGB);
  float v = stats[256+t]*(1.f/NGB) - m*m;
  float val = (g1[r*256+t]-m)*rsqrtf(v+1e-5f);
  sin_[t]=fmaxf(val,0.f);
  __syncthreads();
  if (t<128){
    float acc=bf2[t];
    #pragma unroll 4
    for (int k=0;k<256;k++) acc += sin_[k]*Wf2[k*128+t];
    g2[r*128+t]=acc;
    atomicAdd(&statsH2[t], acc);
    atomicAdd(&statsH2[128+t], acc*acc);
  }
}

__global__ __launch_bounds__(256) void k_head3(const float* __restrict__ g2,
    const float* __restrict__ stats, const float* __restrict__ Wf3,
    const float* __restrict__ bf3, float* __restrict__ out){
  __shared__ float sin_[128];
  int r=blockIdx.x, t=threadIdx.x;
  if (t<128){
    float m = stats[t]*(1.f/NGB);
    float v = stats[128+t]*(1.f/NGB) - m*m;
    float val = (g2[r*128+t]-m)*rsqrtf(v+1e-5f);
    sin_[t]=fmaxf(val,0.f);
  }
  __syncthreads();
  if (t<64){
    float acc=bf3[t];
    #pragma unroll 4
    for (int k=0;k<128;k++) acc += sin_[k]*Wf3[k*64+t];
    out[r*64+t]=acc;
  }
}

extern "C" void kernel_launch(void* const* d_in, const int* in_sizes, int n_in,
                              void* d_out, int out_size, void* d_ws, size_t ws_size,
                              hipStream_t stream){
  const float* x    = (const float*)d_in[0];
  const int*   ei   = (const int*)d_in[1];
  const float* ea   = (const float*)d_in[2];
  const int*   batch= (const int*)d_in[3];
  const float* We1=(const float*)d_in[4];  const float* be1=(const float*)d_in[5];
  const float* We2=(const float*)d_in[6];  const float* be2=(const float*)d_in[7];
  const float* We3=(const float*)d_in[8];  const float* be3=(const float*)d_in[9];
  const float* Wroot=(const float*)d_in[10]; const float* bc1=(const float*)d_in[11];
  const float* Wg1=(const float*)d_in[12]; const float* as1=(const float*)d_in[13];
  const float* ad1=(const float*)d_in[14]; const float* bg1=(const float*)d_in[15];
  const float* Wg2=(const float*)d_in[16]; const float* as2=(const float*)d_in[17];
  const float* ad2=(const float*)d_in[18]; const float* bg2=(const float*)d_in[19];
  const float* Wf1=(const float*)d_in[20]; const float* bf1=(const float*)d_in[21];
  const float* Wf2=(const float*)d_in[22]; const float* bf2=(const float*)d_in[23];
  const float* Wf3=(const float*)d_in[24]; const float* bf3=(const float*)d_in[25];
  (void)in_sizes; (void)n_in; (void)out_size; (void)ws_size;
  float* out = (float*)d_out;
  char* ws = (char*)d_ws;
  const int* srcA = ei;
  const int* dstA = ei + NE;

  size_t off = 0;
  auto take = [&](size_t bytes)->size_t{ size_t r = off; off += (bytes + 255) & ~(size_t)255; return r; };
  // zero region
  size_t o_deg_src = take(NN*4), o_deg_dst = take(NN*4);
  size_t o_fill_src = take(NN*4), o_fill_dst = take(NN*4);
  size_t o_stats0 = take(2*32*4), o_stats1 = take(2*64*4), o_stats2 = take(2*128*4);
  size_t o_statsH1 = take(2*256*4), o_statsH2 = take(2*128*4);
  size_t zero_bytes = off;
  // rest
  size_t o_rp_src = take((NN+1)*4), o_rp_dst = take((NN+1)*4);
  size_t o_pos_src = take((size_t)NE*4);
  size_t o_dstp = take((size_t)NE*4);
  size_t o_srcd = take((size_t)NE*4);
  size_t o_starts = take((NGB+1)*4);
  size_t o_W1p = take(4096*2);
  size_t o_W2p = take(8192*2);
  size_t o_W3h = take((size_t)128*64*8*2);
  size_t o_W3l = take((size_t)128*64*8*2);
  size_t o_t2b = take((size_t)(NE+16)*32*4);       // f16 k-pairs, pad for MFMA tail
  size_t o_Yp  = take((size_t)NN*1024*4);          // f16 k-pairs, kpg-major
  size_t o_xb  = take((size_t)NN*32*4);
  size_t o_agg = take((size_t)NN*32*4);
  size_t o_hW1 = take((size_t)NN*64*2);
  size_t o_scs1 = take(NN*4), o_scd1 = take(NN*4);
  size_t o_h1  = take((size_t)NN*64*4);
  size_t o_hW2 = take((size_t)NN*128*2);
  size_t o_scs2 = take(NN*4), o_scd2 = take(NN*4);
  size_t o_h2  = take((size_t)NN*128*4);
  size_t o_g1  = take(NGB*256*4);
  size_t o_g2  = take(NGB*128*4);

  #define WF(o) ((float*)(ws + (o)))
  #define WI(o) ((int*)(ws + (o)))
  #define WU(o) ((unsigned short*)(ws + (o)))
  #define WW(o) ((unsigned*)(ws + (o)))

  (void)hipMemsetAsync(ws, 0, zero_bytes, stream);
  k_prep<<<625,256,0,stream>>>(srcA,dstA,batch,We1,be1,We2,We3,
                               WI(o_deg_src),WI(o_deg_dst),WI(o_starts),
                               WU(o_W1p),WU(o_W2p),WU(o_W3h),WU(o_W3l));
  k_scan<<<2,1024,0,stream>>>(WI(o_deg_src),WI(o_deg_dst),WI(o_rp_src),WI(o_rp_dst));
  k_fill<<<625,256,0,stream>>>(srcA,dstA,WI(o_rp_src),WI(o_rp_dst),
                               WI(o_fill_src),WI(o_fill_dst),
                               WI(o_pos_src),WI(o_dstp),WI(o_srcd));
  k_big<<<1002,256,0,stream>>>(ea,WU(o_W1p),WU(o_W2p),be2,WI(o_pos_src),WW(o_t2b),
                               x,WU(o_W3h),WU(o_W3l),WW(o_Yp),
                               be3,Wroot,bc1,WF(o_xb),WF(o_agg));
  k_msg4<<<2500,256,0,stream>>>(WW(o_Yp),WF(o_xb),WW(o_t2b),WI(o_rp_src),WI(o_dstp),WF(o_agg));

  k_stats<<<64,256,0,stream>>>(WF(o_agg),NN,32,WF(o_stats0));
  k_gat_linear<32,64><<<640,256,0,stream>>>(WF(o_agg),WF(o_stats0),Wg1,as1,ad1,
                                            WU(o_hW1),WF(o_scs1),WF(o_scd1));
  k_gat_attn5<64><<<2500,256,0,stream>>>(WU(o_hW1),WF(o_scs1),WF(o_scd1),
                                         WI(o_rp_dst),WI(o_srcd),bg1,WF(o_h1));
  k_stats<<<64,256,0,stream>>>(WF(o_h1),NN,64,WF(o_stats1));
  k_gat_linear<64,128><<<640,256,0,stream>>>(WF(o_h1),WF(o_stats1),Wg2,as2,ad2,
                                             WU(o_hW2),WF(o_scs2),WF(o_scd2));
  k_gat_attn5<128><<<2500,256,0,stream>>>(WU(o_hW2),WF(o_scs2),WF(o_scd2),
                                          WI(o_rp_dst),WI(o_srcd),bg2,WF(o_h2));
  k_stats<<<64,256,0,stream>>>(WF(o_h2),NN,128,WF(o_stats2));

  k_poolhead1<<<NGB,256,0,stream>>>(WF(o_h2),WF(o_stats2),WI(o_starts),Wf1,bf1,
                                    WF(o_g1),WF(o_statsH1));
  k_head2<<<NGB,256,0,stream>>>(WF(o_g1),WF(o_statsH1),Wf2,bf2,WF(o_g2),WF(o_statsH2));
  k_head3<<<NGB,256,0,stream>>>(WF(o_g2),WF(o_statsH2),Wf3,bf3,out);
}

// Round 16
// 257.065 us; speedup vs baseline: 4.8405x; 1.0242x over previous
//
#include <hip/hip_runtime.h>

#define NN 10000      // nodes
#define NE 160000     // edges
#define NGB 100       // graphs

typedef __attribute__((ext_vector_type(8))) short s8v;     // 8 x bf16
typedef __attribute__((ext_vector_type(4))) float f4v;     // MFMA accumulator
typedef __attribute__((ext_vector_type(2))) _Float16 h2v;  // half2
typedef __attribute__((ext_vector_type(8))) _Float16 h8v;  // 8 x f16 (MFMA operand)

static __device__ __forceinline__ float lrelu(float v){ return v > 0.f ? v : 0.2f*v; }
static __device__ __forceinline__ unsigned short f2bf(float f){
  unsigned u = __float_as_uint(f);
  u += 0x7fffu + ((u >> 16) & 1u);
  return (unsigned short)(u >> 16);
}
static __device__ __forceinline__ float bf2f(unsigned short h){
  return __uint_as_float(((unsigned)h) << 16);
}
static __device__ __forceinline__ unsigned pkh(float a, float b){
  auto h = __builtin_amdgcn_cvt_pkrtz(a, b);
  return __builtin_bit_cast(unsigned, h);
}
static __device__ __forceinline__ unsigned short f2h(float f){
  _Float16 h = (_Float16)f;
  return __builtin_bit_cast(unsigned short, h);
}
static __device__ __forceinline__ float h2f(unsigned short u){
  return (float)__builtin_bit_cast(_Float16, u);
}
// system-scope store (bypass L1/L2 -> coherent L3)
static __device__ __forceinline__ void stf(float* p, float v){
  __hip_atomic_store(p, v, __ATOMIC_RELAXED, __HIP_MEMORY_SCOPE_SYSTEM);
}
// fence-free grid barrier (small grid; proven correct in R13)
static __device__ __forceinline__ void gridbar(int* bar, int target){
  __syncthreads();
  if (threadIdx.x == 0){
    asm volatile("s_waitcnt vmcnt(0)" ::: "memory");
    __hip_atomic_fetch_add(bar, 1, __ATOMIC_RELAXED, __HIP_MEMORY_SCOPE_SYSTEM);
    while (__hip_atomic_load(bar, __ATOMIC_RELAXED, __HIP_MEMORY_SCOPE_SYSTEM) < target)
      __builtin_amdgcn_s_sleep(8);
    asm volatile("" ::: "memory");
  }
  __syncthreads();
}

// ---------------- prep: degrees + graph bounds + ALL weight packs ----------------
__global__ __launch_bounds__(256) void k_prep(const int* __restrict__ src, const int* __restrict__ dst,
    const int* __restrict__ batch,
    const float* __restrict__ We1, const float* __restrict__ be1,
    const float* __restrict__ We2, const float* __restrict__ We3,
    int* deg_src, int* deg_dst, int* starts,
    unsigned short* __restrict__ W1p, unsigned short* __restrict__ W2p,
    unsigned short* __restrict__ W3h, unsigned short* __restrict__ W3l){
  int i = blockIdx.x*256 + threadIdx.x;
  if (i < NE){ atomicAdd(&deg_src[src[i]],1); atomicAdd(&deg_dst[dst[i]],1); }
  if (i <= NN){
    int cur  = (i==NN) ? NGB : batch[i];
    int prev = (i==0)  ? -1  : batch[i-1];
    for (int b=prev+1; b<=cur; b++) if (b<=NGB) starts[b]=i;
  }
  int tid = threadIdx.x;
  if (blockIdx.x == 32){
    for (int idx=tid; idx<512; idx+=256){
      int j=idx>>6, l=idx&63, col=l&15, g=l>>4;
      int out = j*16+col;
      #pragma unroll
      for (int jj=0;jj<8;jj++){
        int k = g*8+jj;
        float v = (k<16) ? We1[k*128+out] : (k==16 ? be1[out] : 0.f);
        W1p[idx*8+jj] = f2bf(v);
      }
    }
    for (int idx=tid; idx<1024; idx+=256){
      int ft=idx>>6, l=idx&63, col=l&15, g=l>>4;
      int t=ft>>2, jo=ft&3;
      int out = jo*16+col;
      #pragma unroll
      for (int jj=0;jj<8;jj++){
        int k = t*32+g*8+jj;
        W2p[idx*8+jj] = f2bf(We2[k*64+out]);
      }
    }
  } else if (blockIdx.x < 32){
    int idx = blockIdx.x*256 + tid;   // [0, 8192)
    int jt = idx>>6, l = idx&63;
    int j = jt*16 + (l&15);
    int f0 = (l>>4)*8;
    int k = j>>5, o = j&31;
    #pragma unroll
    for (int jj=0;jj<8;jj++){
      float v = We3[(size_t)k*1024 + (size_t)(f0+jj)*32 + o];
      unsigned short h = f2bf(v);
      float r = v - bf2f(h);
      W3h[(size_t)idx*8+jj] = h;
      W3l[(size_t)idx*8+jj] = f2bf(r);
    }
  }
}

__global__ __launch_bounds__(1024) void k_scan(const int* __restrict__ deg_src, const int* __restrict__ deg_dst,
                                               int* rp_src, int* rp_dst){
  const int* deg = (blockIdx.x==0) ? deg_src : deg_dst;
  int* rp = (blockIdx.x==0) ? rp_src : rp_dst;
  __shared__ int part[1024];
  int tid = threadIdx.x;
  const int per = (NN + 1023)/1024;   // 10
  int base = tid*per;
  int s = 0;
  for (int i=0;i<per;i++){ int idx=base+i; if (idx<NN) s += deg[idx]; }
  part[tid]=s; __syncthreads();
  for (int off=1; off<1024; off<<=1){
    int v = part[tid];
    int add = (tid>=off) ? part[tid-off] : 0;
    __syncthreads();
    part[tid] = v + add;
    __syncthreads();
  }
  int run = (tid==0) ? 0 : part[tid-1];
  for (int i=0;i<per;i++){ int idx=base+i; if (idx<NN){ rp[idx]=run; run += deg[idx]; } }
  if (tid==1023) rp[NN] = part[1023];
}

__global__ __launch_bounds__(256) void k_fill(const int* __restrict__ src, const int* __restrict__ dst,
                       const int* __restrict__ rp_src, const int* __restrict__ rp_dst,
                       int* fill_src, int* fill_dst, int* pos_src, int* dstp, int* srcd){
  int i = blockIdx.x*256 + threadIdx.x;
  if (i < NE){
    int s=src[i], d=dst[i];
    int p=rp_src[s]+atomicAdd(&fill_src[s],1); pos_src[i]=p; dstp[p]=d;
    int q=rp_dst[d]+atomicAdd(&fill_dst[d],1); srcd[q]=s;
  }
}

// ---------------- fused: edge-MLP (blocks 0..624) | Y (625..937) | xb/agg (938..1001) ----------------
__global__ __launch_bounds__(256) void k_big(const float* __restrict__ ea,
    const unsigned short* __restrict__ W1p, const unsigned short* __restrict__ W2p,
    const float* __restrict__ be2, const int* __restrict__ pos_src, unsigned* __restrict__ t2b,
    const float* __restrict__ x,
    const unsigned short* __restrict__ W3h, const unsigned short* __restrict__ W3l,
    unsigned* __restrict__ Yp,
    const float* __restrict__ be3, const float* __restrict__ Wroot, const float* __restrict__ bc1,
    float* __restrict__ xb, float* __restrict__ agg){
  __shared__ unsigned short st1[4*2048];
  int bid = blockIdx.x;
  int tid=threadIdx.x, wave=tid>>6, lane=tid&63;
  const f4v fz = {0.f,0.f,0.f,0.f};
  if (bid < 625){
    int c = lane&15, g = lane>>4;
    s8v w1f[8], w2f[16];
    #pragma unroll
    for (int j=0;j<8;j++)  w1f[j] = *(const s8v*)(W1p + (size_t)(j*64+lane)*8);
    #pragma unroll
    for (int q=0;q<16;q++) w2f[q] = *(const s8v*)(W2p + (size_t)(q*64+lane)*8);
    float be2v[16];
    #pragma unroll
    for (int jo=0;jo<4;jo++)
      #pragma unroll
      for (int r=0;r<4;r++) be2v[jo*4+r] = be2[jo*16+g*4+r];
    char* myld = (char*)(st1 + wave*2048);
    for (int base = bid*64; base < NE; base += 625*64){
      int e0 = base + wave*16;
      s8v eaf = {0,0,0,0,0,0,0,0};
      if (g < 2){
        const float* p = ea + (size_t)(e0+c)*16 + g*8;
        float4 a = *(const float4*)p;
        float4 b = *(const float4*)(p+4);
        eaf[0]=(short)f2bf(a.x); eaf[1]=(short)f2bf(a.y); eaf[2]=(short)f2bf(a.z); eaf[3]=(short)f2bf(a.w);
        eaf[4]=(short)f2bf(b.x); eaf[5]=(short)f2bf(b.y); eaf[6]=(short)f2bf(b.z); eaf[7]=(short)f2bf(b.w);
      } else if (g == 2){
        eaf[0] = (short)0x3f80;
      }
      f4v acc1[8];
      #pragma unroll
      for (int j=0;j<8;j++)
        acc1[j] = __builtin_amdgcn_mfma_f32_16x16x32_bf16(w1f[j], eaf, fz, 0, 0, 0);
      #pragma unroll
      for (int j=0;j<8;j++){
        unsigned lo = (unsigned)f2bf(fmaxf(acc1[j][0],0.f)) | ((unsigned)f2bf(fmaxf(acc1[j][1],0.f))<<16);
        unsigned hi = (unsigned)f2bf(fmaxf(acc1[j][2],0.f)) | ((unsigned)f2bf(fmaxf(acc1[j][3],0.f))<<16);
        unsigned off = (unsigned)(c*256 + ((j*32 + g*8) ^ (c<<4)));
        *(uint2*)(myld + off) = make_uint2(lo, hi);
      }
      __syncthreads();
      f4v acc2[4];
      #pragma unroll
      for (int jo=0;jo<4;jo++) acc2[jo] = fz;
      #pragma unroll
      for (int t=0;t<4;t++){
        unsigned off = (unsigned)(c*256 + ((t*64 + g*16) ^ (c<<4)));
        s8v b2 = *(const s8v*)(myld + off);
        #pragma unroll
        for (int jo=0;jo<4;jo++)
          acc2[jo] = __builtin_amdgcn_mfma_f32_16x16x32_bf16(w2f[t*4+jo], b2, acc2[jo], 0, 0, 0);
      }
      int pos = pos_src[e0+c];
      unsigned* orow = t2b + (size_t)pos*32;
      #pragma unroll
      for (int jo=0;jo<4;jo++){
        float v0 = fmaxf(acc2[jo][0] + be2v[jo*4+0], 0.f);
        float v1 = fmaxf(acc2[jo][1] + be2v[jo*4+1], 0.f);
        float v2 = fmaxf(acc2[jo][2] + be2v[jo*4+2], 0.f);
        float v3 = fmaxf(acc2[jo][3] + be2v[jo*4+3], 0.f);
        *(uint2*)(orow + jo*8 + g*2) = make_uint2(pkh(v0,v1), pkh(v2,v3));
      }
      __syncthreads();
    }
  } else if (bid < 938){
    int c = lane&15, g = lane>>4;
    int tile = (bid-625)*2 + (wave>>1);
    if (tile >= 625) return;
    int jhalf = wave&1;
    int n = tile*16 + c;
    const float* xr = x + (size_t)n*32 + g*8;
    float4 xa = *(const float4*)xr;
    float4 xc = *(const float4*)(xr+4);
    float xv[8] = {xa.x,xa.y,xa.z,xa.w,xc.x,xc.y,xc.z,xc.w};
    s8v bh, bl;
    #pragma unroll
    for (int jj=0;jj<8;jj++){
      unsigned short h = f2bf(xv[jj]);
      bh[jj] = (short)h;
      bl[jj] = (short)f2bf(xv[jj] - bf2f(h));
    }
    unsigned* Yrow = Yp + (size_t)n*1024;
    for (int grp=0; grp<4; grp++){
      int jt_g0 = jhalf*64 + grp*16;
      int kpg = jhalf*4 + grp;
      uint4 Q[2][4];
      #pragma unroll
      for (int a=0; a<4; a++){
        #pragma unroll
        for (int b=0; b<2; b++){
          int jt_lo = jt_g0 + 4*a + b;
          int jt_hi = jt_lo + 2;
          s8v AhL = *(const s8v*)(W3h + (size_t)(jt_lo*64 + lane)*8);
          s8v AlL = *(const s8v*)(W3l + (size_t)(jt_lo*64 + lane)*8);
          f4v aL = __builtin_amdgcn_mfma_f32_16x16x32_bf16(AhL, bl, fz, 0, 0, 0);
          aL = __builtin_amdgcn_mfma_f32_16x16x32_bf16(AlL, bh, aL, 0, 0, 0);
          aL = __builtin_amdgcn_mfma_f32_16x16x32_bf16(AhL, bh, aL, 0, 0, 0);
          s8v AhH = *(const s8v*)(W3h + (size_t)(jt_hi*64 + lane)*8);
          s8v AlH = *(const s8v*)(W3l + (size_t)(jt_hi*64 + lane)*8);
          f4v aH = __builtin_amdgcn_mfma_f32_16x16x32_bf16(AhH, bl, fz, 0, 0, 0);
          aH = __builtin_amdgcn_mfma_f32_16x16x32_bf16(AlH, bh, aH, 0, 0, 0);
          aH = __builtin_amdgcn_mfma_f32_16x16x32_bf16(AhH, bh, aH, 0, 0, 0);
          #pragma unroll
          for (int r=0;r<4;r++){
            unsigned pv = pkh(aL[r], aH[r]);
            if (a==0) Q[b][r].x = pv;
            else if (a==1) Q[b][r].y = pv;
            else if (a==2) Q[b][r].z = pv;
            else Q[b][r].w = pv;
          }
        }
      }
      #pragma unroll
      for (int b=0;b<2;b++)
        #pragma unroll
        for (int r=0;r<4;r++){
          int o = b*16 + g*4 + r;
          *(uint4*)(Yrow + kpg*128 + o*4) = Q[b][r];
        }
    }
  } else {
    __shared__ __align__(16) float sx[8][32];
    int b2 = bid - 938;
    int oo = tid & 31, nn = tid >> 5;
    float wb[32], wr[32];
    #pragma unroll
    for (int f=0;f<32;f++){ wb[f]=be3[f*32+oo]; wr[f]=Wroot[f*32+oo]; }
    float bcv = bc1[oo];
    int per = (1250 + 63)/64;
    int g0 = b2*per, g1 = min(g0+per, 1250);
    for (int gi=g0; gi<g1; gi++){
      int nb = gi*8;
      __syncthreads();
      sx[tid>>5][tid&31] = x[(size_t)nb*32 + tid];
      __syncthreads();
      float a1=0.f, a2=0.f;
      #pragma unroll
      for (int f4=0;f4<8;f4++){
        float4 xvv = *(const float4*)(&sx[nn][f4*4]);
        a1 += xvv.x*wb[f4*4+0]+xvv.y*wb[f4*4+1]+xvv.z*wb[f4*4+2]+xvv.w*wb[f4*4+3];
        a2 += xvv.x*wr[f4*4+0]+xvv.y*wr[f4*4+1]+xvv.z*wr[f4*4+2]+xvv.w*wr[f4*4+3];
      }
      xb[(size_t)(nb+nn)*32+oo] = a1;
      agg[(size_t)(nb+nn)*32+oo] = a2 + bcv;
    }
  }
}

// ---------------- msg+aggregate via MFMA f16 ----------------
__global__ __launch_bounds__(256) void k_msg4(const unsigned* __restrict__ Yp,
    const float* __restrict__ xb, const unsigned* __restrict__ t2b,
    const int* __restrict__ rp_src, const int* __restrict__ dstp,
    float* __restrict__ agg){
  int tid=threadIdx.x, w=tid>>6, lane=tid&63;
  int c = lane&15, g = lane>>4;
  int gw = blockIdx.x*4 + w, stride = gridDim.x*4;
  const f4v fz = {0.f,0.f,0.f,0.f};
  for (int n=gw; n<NN; n+=stride){
    int beg=rp_src[n], end=rp_src[n+1];
    if (beg==end) continue;
    const unsigned* Yr = Yp + (size_t)n*1024;
    h8v B[2][2];
    #pragma unroll
    for (int kt=0;kt<2;kt++)
      #pragma unroll
      for (int jn=0;jn<2;jn++)
        B[kt][jn] = __builtin_bit_cast(h8v, *(const uint4*)(Yr + (kt*4+g)*128 + (jn*16+c)*4));
    float xq0 = xb[(size_t)n*32 + c];
    float xq1 = xb[(size_t)n*32 + c + 16];
    for (int eb=beg; eb<end; eb+=16){
      const unsigned* tr = t2b + (size_t)(eb + c)*32;
      h8v A0 = __builtin_bit_cast(h8v, *(const uint4*)(tr + g*4));
      h8v A1 = __builtin_bit_cast(h8v, *(const uint4*)(tr + 16 + g*4));
      f4v acc0 = __builtin_amdgcn_mfma_f32_16x16x32_f16(A0, B[0][0], fz, 0, 0, 0);
      acc0 = __builtin_amdgcn_mfma_f32_16x16x32_f16(A1, B[1][0], acc0, 0, 0, 0);
      f4v acc1 = __builtin_amdgcn_mfma_f32_16x16x32_f16(A0, B[0][1], fz, 0, 0, 0);
      acc1 = __builtin_amdgcn_mfma_f32_16x16x32_f16(A1, B[1][1], acc1, 0, 0, 0);
      #pragma unroll
      for (int r=0;r<4;r++){
        int p = eb + g*4 + r;
        if (p < end){
          int d = dstp[p];
          float* ap = agg + (size_t)d*32;
          unsafeAtomicAdd(ap + c,      acc0[r] + xq0);
          unsafeAtomicAdd(ap + c + 16, acc1[r] + xq1);
        }
      }
    }
  }
}

// ---------------- column stats (sum, sumsq); stats pre-zeroed ----------------
__global__ __launch_bounds__(256) void k_stats(const float* __restrict__ buf, int nrows, int ncols,
                                               float* __restrict__ stats){
  int tid = threadIdx.x;
  int c  = tid % ncols;
  int r0 = tid / ncols;
  int rp = 256 / ncols;
  float s1=0.f, s2=0.f;
  for (long long base=(long long)blockIdx.x*rp; base<nrows; base+=(long long)gridDim.x*rp){
    int r = (int)base + r0;
    if (r < nrows){
      float v = buf[(size_t)r*ncols + c];
      s1 += v; s2 += v*v;
    }
  }
  __shared__ float A[256], B[256];
  A[tid]=s1; B[tid]=s2; __syncthreads();
  if (tid < ncols){
    float t1=0.f, t2=0.f;
    for (int gg=0; gg<256/ncols; gg++){ t1 += A[gg*ncols+tid]; t2 += B[gg*ncols+tid]; }
    atomicAdd(&stats[tid], t1);
    atomicAdd(&stats[ncols+tid], t2);
  }
}

// ---------------- GAT linear: in=relu(bn(raw)); hWh=f16(in@W); sc_s,sc_d ----------------
template<int FIN, int FOUT>
__global__ __launch_bounds__(256) void k_gat_linear(const float* __restrict__ raw,
    const float* __restrict__ stats, const float* __restrict__ W,
    const float* __restrict__ avs, const float* __restrict__ avd,
    unsigned short* __restrict__ hWh, float* __restrict__ sc_s, float* __restrict__ sc_d){
  __shared__ float sW[FIN*FOUT];
  __shared__ float sA[FOUT], sD[FOUT];
  __shared__ float sScale[FIN], sShift[FIN];
  __shared__ float sIn[4][FIN];
  int tid = threadIdx.x;
  for (int i=tid;i<FIN*FOUT;i+=256) sW[i]=W[i];
  if (tid<FOUT){ sA[tid]=avs[tid]; sD[tid]=avd[tid]; }
  if (tid<FIN){
    float m = stats[tid]*(1.f/NN);
    float v = stats[FIN+tid]*(1.f/NN) - m*m;
    float s = rsqrtf(v + 1e-5f);
    sScale[tid]=s; sShift[tid]=-m*s;
  }
  __syncthreads();
  int wave=tid>>6, lane=tid&63;
  for (int nb = blockIdx.x*4; nb < NN; nb += gridDim.x*4){
    int n = nb + wave;
    bool act = n < NN;
    if (act){
      for (int ff=lane; ff<FIN; ff+=64){
        float vv = raw[(size_t)n*FIN+ff]*sScale[ff]+sShift[ff];
        sIn[wave][ff] = fmaxf(vv, 0.f);
      }
    }
    __syncthreads();
    if (act){
      float out0=0.f, out1=0.f;
      #pragma unroll
      for (int ff=0; ff<FIN; ff++){
        float xv = sIn[wave][ff];
        out0 += xv*sW[ff*FOUT+lane];
        if constexpr (FOUT > 64) out1 += xv*sW[ff*FOUT+lane+64];
      }
      hWh[(size_t)n*FOUT + lane] = f2h(out0);
      float ps = out0*sA[lane], pd = out0*sD[lane];
      if constexpr (FOUT > 64){
        hWh[(size_t)n*FOUT + lane + 64] = f2h(out1);
        ps += out1*sA[lane+64]; pd += out1*sD[lane+64];
      }
      #pragma unroll
      for (int off=32;off>0;off>>=1){ ps += __shfl_down(ps,off); pd += __shfl_down(pd,off); }
      if (lane==0){ sc_s[n]=ps; sc_d[n]=pd; }
    }
    __syncthreads();
  }
}

// ---------------- GAT attention: 1 wave/node, inline score gather, unrolled hW gathers ----------------
template<int F>
__global__ __launch_bounds__(256) void k_gat_attn5(const unsigned short* __restrict__ hWh,
    const float* __restrict__ sc_s, const float* __restrict__ sc_d,
    const int* __restrict__ rp_dst, const int* __restrict__ srcd,
    const float* __restrict__ bias, float* __restrict__ outraw){
  int tid=threadIdx.x, w=tid>>6, lane=tid&63;
  int gw = blockIdx.x*4 + w, stride = gridDim.x*4;
  for (int n=gw; n<NN; n+=stride){
    int beg=rp_dst[n], end=rp_dst[n+1];
    float scd = sc_d[n];
    float M=-3e38f, S=0.f, acc0=0.f, acc1=0.f;
    for (int base=beg; base<end; base+=64){
      int nb = min(64, end-base);
      float sc=-3e38f; int si=0;
      if (lane<nb){ si = srcd[base+lane]; sc = lrelu(sc_s[si]+scd); }
      float cm=sc;
      #pragma unroll
      for (int off=32;off>0;off>>=1) cm = fmaxf(cm, __shfl_xor(cm,off));
      float Mn = fmaxf(M, cm);
      float p = (lane<nb) ? __expf(sc-Mn) : 0.f;
      float ps=p;
      #pragma unroll
      for (int off=32;off>0;off>>=1) ps += __shfl_xor(ps,off);
      float scale = __expf(M-Mn);
      S = S*scale + ps;
      acc0*=scale; acc1*=scale;
      int jj=0;
      for (; jj+4<=nb; jj+=4){
        float p0=__shfl(p,jj), p1=__shfl(p,jj+1), p2=__shfl(p,jj+2), p3=__shfl(p,jj+3);
        int   q0=__shfl(si,jj), q1=__shfl(si,jj+1), q2=__shfl(si,jj+2), q3=__shfl(si,jj+3);
        if constexpr (F==128){
          unsigned u0 = *(const unsigned*)(hWh + (size_t)q0*128 + 2*lane);
          unsigned u1 = *(const unsigned*)(hWh + (size_t)q1*128 + 2*lane);
          unsigned u2 = *(const unsigned*)(hWh + (size_t)q2*128 + 2*lane);
          unsigned u3 = *(const unsigned*)(hWh + (size_t)q3*128 + 2*lane);
          acc0 += p0*h2f((unsigned short)(u0&0xffffu)); acc1 += p0*h2f((unsigned short)(u0>>16));
          acc0 += p1*h2f((unsigned short)(u1&0xffffu)); acc1 += p1*h2f((unsigned short)(u1>>16));
          acc0 += p2*h2f((unsigned short)(u2&0xffffu)); acc1 += p2*h2f((unsigned short)(u2>>16));
          acc0 += p3*h2f((unsigned short)(u3&0xffffu)); acc1 += p3*h2f((unsigned short)(u3>>16));
        } else {
          float v0 = h2f(hWh[(size_t)q0*64+lane]);
          float v1 = h2f(hWh[(size_t)q1*64+lane]);
          float v2 = h2f(hWh[(size_t)q2*64+lane]);
          float v3 = h2f(hWh[(size_t)q3*64+lane]);
          acc0 += p0*v0 + p1*v1 + p2*v2 + p3*v3;
        }
      }
      for (; jj<nb; jj++){
        float pj=__shfl(p,jj); int qj=__shfl(si,jj);
        if constexpr (F==128){
          unsigned u = *(const unsigned*)(hWh + (size_t)qj*128 + 2*lane);
          acc0 += pj*h2f((unsigned short)(u&0xffffu));
          acc1 += pj*h2f((unsigned short)(u>>16));
        } else {
          acc0 += pj*h2f(hWh[(size_t)qj*64+lane]);
        }
      }
      M = Mn;
    }
    float sself = lrelu(sc_s[n]+scd);
    float Mn = fmaxf(M, sself);
    float scale = __expf(M-Mn);
    float pself = __expf(sself-Mn);
    S = S*scale + pself;
    acc0*=scale; acc1*=scale;
    float inv = 1.f/(S+1e-16f);
    if constexpr (F==128){
      unsigned u = *(const unsigned*)(hWh + (size_t)n*128 + 2*lane);
      acc0 += pself*h2f((unsigned short)(u&0xffffu));
      acc1 += pself*h2f((unsigned short)(u>>16));
      float ox = acc0*inv + bias[2*lane];
      float oy = acc1*inv + bias[2*lane+1];
      *(float2*)(outraw + (size_t)n*128 + 2*lane) = make_float2(ox, oy);
    } else {
      acc0 += pself*h2f(hWh[(size_t)n*64+lane]);
      outraw[(size_t)n*64+lane] = acc0*inv + bias[lane];
    }
  }
}

// ---------------- fused tail: stats(h2) -> pool+head1 -> head2 -> head3 (100 blocks, 3 barriers) ----------------
__global__ __launch_bounds__(256) void k_tail(const float* __restrict__ h2raw,
    const int* __restrict__ starts,
    const float* __restrict__ Wf1, const float* __restrict__ bf1,
    const float* __restrict__ Wf2, const float* __restrict__ bf2,
    const float* __restrict__ Wf3, const float* __restrict__ bf3,
    float* __restrict__ stats2, float* __restrict__ statsH1, float* __restrict__ statsH2,
    float* __restrict__ g1, float* __restrict__ g2, float* __restrict__ out,
    int* __restrict__ bar){
  __shared__ float sm0[256], sm1[256];
  int b=blockIdx.x, t=threadIdx.x;
  // --- phase 0: stats of h2 (all 100 blocks) ---
  {
    int c = t & 127, r0 = t >> 7;      // rp = 2
    float s1=0.f, s2=0.f;
    for (int base=b*2; base<NN; base+=100*2){
      int r = base + r0;
      if (r < NN){
        float v = h2raw[(size_t)r*128 + c];
        s1 += v; s2 += v*v;
      }
    }
    sm0[t]=s1; sm1[t]=s2; __syncthreads();
    if (t < 128){
      atomicAdd(&stats2[t],     sm0[t]+sm0[128+t]);
      atomicAdd(&stats2[128+t], sm1[t]+sm1[128+t]);
    }
  }
  gridbar(bar, 100);
  // --- phase 1: pool (bn+relu) + head1 ---
  {
    __shared__ float sc[128], sh[128], red[256], sg[128];
    if (t<128){
      float m = stats2[t]*(1.f/NN);
      float v = stats2[128+t]*(1.f/NN) - m*m;
      float s = rsqrtf(v+1e-5f);
      sc[t]=s; sh[t]=-m*s;
    }
    __syncthreads();
    int s0=starts[b], s1=starts[b+1];
    int f=t&127, half=t>>7;
    float acc=0.f;
    for (int n=s0+half;n<s1;n+=2){
      float v = h2raw[(size_t)n*128+f]*sc[f]+sh[f];
      acc += fmaxf(v,0.f);
    }
    red[t]=acc; __syncthreads();
    if (half==0){
      int cnt = s1-s0;
      sg[f] = (red[f]+red[128+f]) / fmaxf((float)cnt, 1.f);
    }
    __syncthreads();
    float a = bf1[t];
    #pragma unroll 4
    for (int k=0;k<128;k++) a += sg[k]*Wf1[k*256+t];
    stf(&g1[b*256+t], a);
    atomicAdd(&statsH1[t], a);
    atomicAdd(&statsH1[256+t], a*a);
  }
  gridbar(bar, 200);
  // --- phase 2: head2 ---
  {
    __shared__ float sin_[256];
    float m = statsH1[t]*(1.f/NGB);
    float v = statsH1[256+t]*(1.f/NGB) - m*m;
    float val = (g1[b*256+t]-m)*rsqrtf(v+1e-5f);
    sin_[t]=fmaxf(val,0.f);
    __syncthreads();
    if (t<128){
      float acc=bf2[t];
      #pragma unroll 4
      for (int k=0;k<256;k++) acc += sin_[k]*Wf2[k*128+t];
      stf(&g2[b*128+t], acc);
      atomicAdd(&statsH2[t], acc);
      atomicAdd(&statsH2[128+t], acc*acc);
    }
  }
  gridbar(bar, 300);
  // --- phase 3: head3 ---
  {
    __shared__ float sin_[128];
    if (t<128){
      float m = statsH2[t]*(1.f/NGB);
      float v = statsH2[128+t]*(1.f/NGB) - m*m;
      float val = (g2[b*128+t]-m)*rsqrtf(v+1e-5f);
      sin_[t]=fmaxf(val,0.f);
    }
    __syncthreads();
    if (t<64){
      float acc=bf3[t];
      #pragma unroll 4
      for (int k=0;k<128;k++) acc += sin_[k]*Wf3[k*64+t];
      out[b*64+t]=acc;
    }
  }
}

extern "C" void kernel_launch(void* const* d_in, const int* in_sizes, int n_in,
                              void* d_out, int out_size, void* d_ws, size_t ws_size,
                              hipStream_t stream){
  const float* x    = (const float*)d_in[0];
  const int*   ei   = (const int*)d_in[1];
  const float* ea   = (const float*)d_in[2];
  const int*   batch= (const int*)d_in[3];
  const float* We1=(const float*)d_in[4];  const float* be1=(const float*)d_in[5];
  const float* We2=(const float*)d_in[6];  const float* be2=(const float*)d_in[7];
  const float* We3=(const float*)d_in[8];  const float* be3=(const float*)d_in[9];
  const float* Wroot=(const float*)d_in[10]; const float* bc1=(const float*)d_in[11];
  const float* Wg1=(const float*)d_in[12]; const float* as1=(const float*)d_in[13];
  const float* ad1=(const float*)d_in[14]; const float* bg1=(const float*)d_in[15];
  const float* Wg2=(const float*)d_in[16]; const float* as2=(const float*)d_in[17];
  const float* ad2=(const float*)d_in[18]; const float* bg2=(const float*)d_in[19];
  const float* Wf1=(const float*)d_in[20]; const float* bf1=(const float*)d_in[21];
  const float* Wf2=(const float*)d_in[22]; const float* bf2=(const float*)d_in[23];
  const float* Wf3=(const float*)d_in[24]; const float* bf3=(const float*)d_in[25];
  (void)in_sizes; (void)n_in; (void)out_size; (void)ws_size;
  float* out = (float*)d_out;
  char* ws = (char*)d_ws;
  const int* srcA = ei;
  const int* dstA = ei + NE;

  size_t off = 0;
  auto take = [&](size_t bytes)->size_t{ size_t r = off; off += (bytes + 255) & ~(size_t)255; return r; };
  // zero region (in-graph memset -> re-zeroed every replay, incl. barrier counter)
  size_t o_deg_src = take(NN*4), o_deg_dst = take(NN*4);
  size_t o_fill_src = take(NN*4), o_fill_dst = take(NN*4);
  size_t o_stats0 = take(2*32*4), o_stats1 = take(2*64*4), o_stats2 = take(2*128*4);
  size_t o_statsH1 = take(2*256*4), o_statsH2 = take(2*128*4);
  size_t o_bar = take(256);
  size_t zero_bytes = off;
  // rest
  size_t o_rp_src = take((NN+1)*4), o_rp_dst = take((NN+1)*4);
  size_t o_pos_src = take((size_t)NE*4);
  size_t o_dstp = take((size_t)NE*4);
  size_t o_srcd = take((size_t)NE*4);
  size_t o_starts = take((NGB+1)*4);
  size_t o_W1p = take(4096*2);
  size_t o_W2p = take(8192*2);
  size_t o_W3h = take((size_t)128*64*8*2);
  size_t o_W3l = take((size_t)128*64*8*2);
  size_t o_t2b = take((size_t)(NE+16)*32*4);       // f16 k-pairs, pad for MFMA tail
  size_t o_Yp  = take((size_t)NN*1024*4);          // f16 k-pairs, kpg-major
  size_t o_xb  = take((size_t)NN*32*4);
  size_t o_agg = take((size_t)NN*32*4);
  size_t o_hW1 = take((size_t)NN*64*2);
  size_t o_scs1 = take(NN*4), o_scd1 = take(NN*4);
  size_t o_h1  = take((size_t)NN*64*4);
  size_t o_hW2 = take((size_t)NN*128*2);
  size_t o_scs2 = take(NN*4), o_scd2 = take(NN*4);
  size_t o_h2  = take((size_t)NN*128*4);
  size_t o_g1  = take(NGB*256*4);
  size_t o_g2  = take(NGB*128*4);

  #define WF(o) ((float*)(ws + (o)))
  #define WI(o) ((int*)(ws + (o)))
  #define WU(o) ((unsigned short*)(ws + (o)))
  #define WW(o) ((unsigned*)(ws + (o)))

  (void)hipMemsetAsync(ws, 0, zero_bytes, stream);
  k_prep<<<625,256,0,stream>>>(srcA,dstA,batch,We1,be1,We2,We3,
                               WI(o_deg_src),WI(o_deg_dst),WI(o_starts),
                               WU(o_W1p),WU(o_W2p),WU(o_W3h),WU(o_W3l));
  k_scan<<<2,1024,0,stream>>>(WI(o_deg_src),WI(o_deg_dst),WI(o_rp_src),WI(o_rp_dst));
  k_fill<<<625,256,0,stream>>>(srcA,dstA,WI(o_rp_src),WI(o_rp_dst),
                               WI(o_fill_src),WI(o_fill_dst),
                               WI(o_pos_src),WI(o_dstp),WI(o_srcd));
  k_big<<<1002,256,0,stream>>>(ea,WU(o_W1p),WU(o_W2p),be2,WI(o_pos_src),WW(o_t2b),
                               x,WU(o_W3h),WU(o_W3l),WW(o_Yp),
                               be3,Wroot,bc1,WF(o_xb),WF(o_agg));
  k_msg4<<<2500,256,0,stream>>>(WW(o_Yp),WF(o_xb),WW(o_t2b),WI(o_rp_src),WI(o_dstp),WF(o_agg));

  k_stats<<<64,256,0,stream>>>(WF(o_agg),NN,32,WF(o_stats0));
  k_gat_linear<32,64><<<640,256,0,stream>>>(WF(o_agg),WF(o_stats0),Wg1,as1,ad1,
                                            WU(o_hW1),WF(o_scs1),WF(o_scd1));
  k_gat_attn5<64><<<2500,256,0,stream>>>(WU(o_hW1),WF(o_scs1),WF(o_scd1),
                                         WI(o_rp_dst),WI(o_srcd),bg1,WF(o_h1));
  k_stats<<<64,256,0,stream>>>(WF(o_h1),NN,64,WF(o_stats1));
  k_gat_linear<64,128><<<640,256,0,stream>>>(WF(o_h1),WF(o_stats1),Wg2,as2,ad2,
                                             WU(o_hW2),WF(o_scs2),WF(o_scd2));
  k_gat_attn5<128><<<2500,256,0,stream>>>(WU(o_hW2),WF(o_scs2),WF(o_scd2),
                                          WI(o_rp_dst),WI(o_srcd),bg2,WF(o_h2));

  k_tail<<<NGB,256,0,stream>>>(WF(o_h2),WI(o_starts),Wf1,bf1,Wf2,bf2,Wf3,bf3,
                               WF(o_stats2),WF(o_statsH1),WF(o_statsH2),
                               WF(o_g1),WF(o_g2),out,WI(o_bar));
}